// Round 1
// baseline (257.029 us; speedup 1.0000x reference)
//
#include <hip/hip_runtime.h>
#include <math.h>

#define NROWS 4096
#define DIN   1024
#define DOUT  256
#define NCHUNK 16   // column chunks for the Gram kernel (4096/16 = 256 cols each)

// ---------------------------------------------------------------------------
// Kernel 1: h = x @ W + b   (M=4096, K=1024, N=256), fp32 tiled GEMM
// BM=BN=64, BK=16, 256 threads, 4x4 micro-tile per thread.
// ---------------------------------------------------------------------------
__global__ __launch_bounds__(256) void gemm_xw(const float* __restrict__ x,
                                               const float* __restrict__ W,
                                               const float* __restrict__ b,
                                               float* __restrict__ h) {
    __shared__ __align__(16) float As[16][68];  // [k][m], stride 68 floats (272B, 16B-aligned rows)
    __shared__ __align__(16) float Bs[16][68];  // [k][n]
    const int tid = threadIdx.x;
    const int tx = tid & 15, ty = tid >> 4;
    const int i0 = blockIdx.y * 64;
    const int n0 = blockIdx.x * 64;

    const int rowA = tid >> 2;          // 0..63
    const int colA = (tid & 3) << 2;    // 0,4,8,12
    const int rowB = tid >> 4;          // 0..15
    const int colB = (tid & 15) << 2;   // 0..60

    float acc[4][4] = {};

    for (int k0 = 0; k0 < DIN; k0 += 16) {
        float4 av = *(const float4*)&x[(i0 + rowA) * DIN + k0 + colA];
        float4 bv = *(const float4*)&W[(k0 + rowB) * DOUT + n0 + colB];
        __syncthreads();
        As[colA + 0][rowA] = av.x;
        As[colA + 1][rowA] = av.y;
        As[colA + 2][rowA] = av.z;
        As[colA + 3][rowA] = av.w;
        *(float4*)&Bs[rowB][colB] = bv;
        __syncthreads();
#pragma unroll
        for (int k = 0; k < 16; ++k) {
            float4 a  = *(const float4*)&As[k][ty * 4];
            float4 bb = *(const float4*)&Bs[k][tx * 4];
            float am[4] = {a.x, a.y, a.z, a.w};
            float bn[4] = {bb.x, bb.y, bb.z, bb.w};
#pragma unroll
            for (int m = 0; m < 4; ++m)
#pragma unroll
                for (int n = 0; n < 4; ++n)
                    acc[m][n] = fmaf(am[m], bn[n], acc[m][n]);
        }
    }

#pragma unroll
    for (int m = 0; m < 4; ++m) {
        const int gi = i0 + ty * 4 + m;
        const int gn = n0 + tx * 4;
        float4 outv;
        outv.x = acc[m][0] + b[gn + 0];
        outv.y = acc[m][1] + b[gn + 1];
        outv.z = acc[m][2] + b[gn + 2];
        outv.w = acc[m][3] + b[gn + 3];
        *(float4*)&h[gi * DOUT + gn] = outv;
    }
}

// ---------------------------------------------------------------------------
// Kernel 2: sq[i] = sum_k h[i][k]^2   (one 64-lane wave per row, 4 cols/lane)
// ---------------------------------------------------------------------------
__global__ __launch_bounds__(64) void rowsq(const float* __restrict__ h,
                                            float* __restrict__ sq) {
    const int row = blockIdx.x;
    const int lane = threadIdx.x;
    float4 v = *(const float4*)&h[row * DOUT + lane * 4];
    float s = v.x * v.x + v.y * v.y + v.z * v.z + v.w * v.w;
#pragma unroll
    for (int off = 32; off; off >>= 1) s += __shfl_down(s, off);
    if (lane == 0) sq[row] = s;
}

// ---------------------------------------------------------------------------
// Kernel 3: Gram GEMM h @ h^T with fused hardest-pos/neg epilogue.
// Each block: 64 anchor rows (blockIdx.y) x one 256-col chunk (blockIdx.x).
// Tracks max over same-class / min over diff-class of (sq_j - 2*g_ij),
// writes per-chunk partials pmax/pmin [4096 x NCHUNK].
// ---------------------------------------------------------------------------
__global__ __launch_bounds__(256) void hardest_partials(
    const float* __restrict__ h, const float* __restrict__ sq,
    const int* __restrict__ targets,
    float* __restrict__ pmax, float* __restrict__ pmin) {
    __shared__ __align__(16) float As[16][68];
    __shared__ __align__(16) float Bs[16][68];
    __shared__ int   tgtI[64];
    __shared__ int   tgtJ[64];
    __shared__ float sqJ[64];
    __shared__ float red[64][17];

    const int tid = threadIdx.x;
    const int tx = tid & 15, ty = tid >> 4;
    const int i0 = blockIdx.y * 64;
    const int c0 = blockIdx.x * (NROWS / NCHUNK);  // 256-wide column chunk

    const int rowL = tid >> 2;
    const int colL = (tid & 3) << 2;

    if (tid < 64) tgtI[tid] = targets[i0 + tid];
    __syncthreads();
    int ti[4];
#pragma unroll
    for (int m = 0; m < 4; ++m) ti[m] = tgtI[ty * 4 + m];

    float bmax[4] = {-INFINITY, -INFINITY, -INFINITY, -INFINITY};
    float bmin[4] = { INFINITY,  INFINITY,  INFINITY,  INFINITY};

    for (int jt = 0; jt < 4; ++jt) {
        const int j0 = c0 + jt * 64;
        float acc[4][4] = {};
        for (int k0 = 0; k0 < DOUT; k0 += 16) {
            float4 av = *(const float4*)&h[(i0 + rowL) * DOUT + k0 + colL];
            float4 bv = *(const float4*)&h[(j0 + rowL) * DOUT + k0 + colL];
            __syncthreads();  // protect prior-iter LDS reads (and epilogue reads of tgtJ/sqJ)
            As[colL + 0][rowL] = av.x;
            As[colL + 1][rowL] = av.y;
            As[colL + 2][rowL] = av.z;
            As[colL + 3][rowL] = av.w;
            Bs[colL + 0][rowL] = bv.x;
            Bs[colL + 1][rowL] = bv.y;
            Bs[colL + 2][rowL] = bv.z;
            Bs[colL + 3][rowL] = bv.w;
            if (k0 == 0 && tid < 64) {
                tgtJ[tid] = targets[j0 + tid];
                sqJ[tid]  = sq[j0 + tid];
            }
            __syncthreads();
#pragma unroll
            for (int k = 0; k < 16; ++k) {
                float4 a  = *(const float4*)&As[k][ty * 4];
                float4 bb = *(const float4*)&Bs[k][tx * 4];
                float am[4] = {a.x, a.y, a.z, a.w};
                float bn[4] = {bb.x, bb.y, bb.z, bb.w};
#pragma unroll
                for (int m = 0; m < 4; ++m)
#pragma unroll
                    for (int n = 0; n < 4; ++n)
                        acc[m][n] = fmaf(am[m], bn[n], acc[m][n]);
            }
        }
        // fused epilogue: masked running max/min on (sq_j - 2*g_ij)
#pragma unroll
        for (int n = 0; n < 4; ++n) {
            const int jj = tx * 4 + n;
            const float sv = sqJ[jj];
            const int   tj = tgtJ[jj];
#pragma unroll
            for (int m = 0; m < 4; ++m) {
                const float v = sv - 2.0f * acc[m][n];
                if (ti[m] == tj) bmax[m] = fmaxf(bmax[m], v);
                else             bmin[m] = fminf(bmin[m], v);
            }
        }
    }

    // reduce across the 16 column-groups (tx) for each of the 64 rows
    __syncthreads();
#pragma unroll
    for (int m = 0; m < 4; ++m) red[ty * 4 + m][tx] = bmax[m];
    __syncthreads();
    if (tid < 64) {
        float v = red[tid][0];
#pragma unroll
        for (int c = 1; c < 16; ++c) v = fmaxf(v, red[tid][c]);
        pmax[(i0 + tid) * NCHUNK + blockIdx.x] = v;
    }
    __syncthreads();
#pragma unroll
    for (int m = 0; m < 4; ++m) red[ty * 4 + m][tx] = bmin[m];
    __syncthreads();
    if (tid < 64) {
        float v = red[tid][0];
#pragma unroll
        for (int c = 1; c < 16; ++c) v = fminf(v, red[tid][c]);
        pmin[(i0 + tid) * NCHUNK + blockIdx.x] = v;
    }
}

// ---------------------------------------------------------------------------
// Kernel 4: combine chunk partials, per-row loss, sum -> d_out[0]
// ---------------------------------------------------------------------------
__global__ __launch_bounds__(256) void finalize(const float* __restrict__ sq,
                                                const float* __restrict__ pmax,
                                                const float* __restrict__ pmin,
                                                float* __restrict__ out) {
    __shared__ float wsum[4];
    const int i = blockIdx.x * 256 + threadIdx.x;
    float mp = -INFINITY, mn = INFINITY;
#pragma unroll
    for (int c = 0; c < NCHUNK; ++c) {
        mp = fmaxf(mp, pmax[i * NCHUNK + c]);
        mn = fminf(mn, pmin[i * NCHUNK + c]);
    }
    const float si = sq[i];
    const float hp = sqrtf(fmaxf(si + mp, 0.0f));
    const float hn = sqrtf(fmaxf(si + mn, 0.0f));
    const float d  = hp - hn;
    // stable log1p(exp(d))
    float li = fmaxf(d, 0.0f) + log1pf(expf(-fabsf(d)));
#pragma unroll
    for (int off = 32; off; off >>= 1) li += __shfl_down(li, off);
    const int lane = threadIdx.x & 63, w = threadIdx.x >> 6;
    if (lane == 0) wsum[w] = li;
    __syncthreads();
    if (threadIdx.x == 0)
        atomicAdd(out, wsum[0] + wsum[1] + wsum[2] + wsum[3]);
}

// ---------------------------------------------------------------------------
extern "C" void kernel_launch(void* const* d_in, const int* in_sizes, int n_in,
                              void* d_out, int out_size, void* d_ws, size_t ws_size,
                              hipStream_t stream) {
    const float* x       = (const float*)d_in[0];
    const float* W       = (const float*)d_in[1];
    const float* b       = (const float*)d_in[2];
    const int*   targets = (const int*)d_in[3];
    float* out = (float*)d_out;

    float* h    = (float*)d_ws;                 // 4096*256
    float* sq   = h + NROWS * DOUT;             // 4096
    float* pmax = sq + NROWS;                   // 4096*NCHUNK
    float* pmin = pmax + NROWS * NCHUNK;        // 4096*NCHUNK

    hipMemsetAsync(d_out, 0, sizeof(float), stream);

    gemm_xw<<<dim3(DOUT / 64, NROWS / 64), 256, 0, stream>>>(x, W, b, h);
    rowsq<<<NROWS, 64, 0, stream>>>(h, sq);
    hardest_partials<<<dim3(NCHUNK, NROWS / 64), 256, 0, stream>>>(h, sq, targets, pmax, pmin);
    finalize<<<NROWS / 256, 256, 0, stream>>>(sq, pmax, pmin, out);
}

// Round 2
// 190.169 us; speedup vs baseline: 1.3516x; 1.3516x over previous
//
#include <hip/hip_runtime.h>
#include <math.h>

#define NROWS 4096
#define DIN   1024
#define DOUT  256
#define NCHUNK 32        // j-chunks (one 128-col block each) for the Gram kernel

using bfrag = __attribute__((ext_vector_type(8))) short;  // 8 bf16 (4 VGPRs)
using ffrag = __attribute__((ext_vector_type(4))) float;  // 4 fp32 acc

// round-to-nearest-even fp32 -> bf16 (values are finite; no NaN handling needed)
static __device__ __forceinline__ unsigned short f2bf(float f) {
    unsigned int u = __float_as_uint(f);
    u = (u + 0x7fffu + ((u >> 16) & 1u)) >> 16;
    return (unsigned short)u;
}

// ---------------------------------------------------------------------------
// Kernel 1: h = x @ W + b   (M=4096, K=1024, N=256), fp32 tiled GEMM.
// Also emits hb = bf16(h) for the MFMA Gram kernel.
// ---------------------------------------------------------------------------
__global__ __launch_bounds__(256) void gemm_xw(const float* __restrict__ x,
                                               const float* __restrict__ W,
                                               const float* __restrict__ b,
                                               float* __restrict__ h,
                                               unsigned short* __restrict__ hb) {
    __shared__ __align__(16) float As[16][68];  // [k][m]
    __shared__ __align__(16) float Bs[16][68];  // [k][n]
    const int tid = threadIdx.x;
    const int tx = tid & 15, ty = tid >> 4;
    const int i0 = blockIdx.y * 64;
    const int n0 = blockIdx.x * 64;

    const int rowA = tid >> 2;          // 0..63
    const int colA = (tid & 3) << 2;    // 0,4,8,12
    const int rowB = tid >> 4;          // 0..15
    const int colB = (tid & 15) << 2;   // 0..60

    float acc[4][4] = {};

    for (int k0 = 0; k0 < DIN; k0 += 16) {
        float4 av = *(const float4*)&x[(i0 + rowA) * DIN + k0 + colA];
        float4 bv = *(const float4*)&W[(k0 + rowB) * DOUT + n0 + colB];
        __syncthreads();
        As[colA + 0][rowA] = av.x;
        As[colA + 1][rowA] = av.y;
        As[colA + 2][rowA] = av.z;
        As[colA + 3][rowA] = av.w;
        *(float4*)&Bs[rowB][colB] = bv;
        __syncthreads();
#pragma unroll
        for (int k = 0; k < 16; ++k) {
            float4 a  = *(const float4*)&As[k][ty * 4];
            float4 bb = *(const float4*)&Bs[k][tx * 4];
            float am[4] = {a.x, a.y, a.z, a.w};
            float bn[4] = {bb.x, bb.y, bb.z, bb.w};
#pragma unroll
            for (int m = 0; m < 4; ++m)
#pragma unroll
                for (int n = 0; n < 4; ++n)
                    acc[m][n] = fmaf(am[m], bn[n], acc[m][n]);
        }
    }

#pragma unroll
    for (int m = 0; m < 4; ++m) {
        const int gi = i0 + ty * 4 + m;
        const int gn = n0 + tx * 4;
        float4 outv;
        outv.x = acc[m][0] + b[gn + 0];
        outv.y = acc[m][1] + b[gn + 1];
        outv.z = acc[m][2] + b[gn + 2];
        outv.w = acc[m][3] + b[gn + 3];
        *(float4*)&h[gi * DOUT + gn] = outv;
        ushort4 hv;
        hv.x = f2bf(outv.x);
        hv.y = f2bf(outv.y);
        hv.z = f2bf(outv.z);
        hv.w = f2bf(outv.w);
        *(ushort4*)&hb[gi * DOUT + gn] = hv;
    }
}

// ---------------------------------------------------------------------------
// Kernel 2: sq[i] = sum_k h[i][k]^2  (fp32 h, one wave per row)
// ---------------------------------------------------------------------------
__global__ __launch_bounds__(64) void rowsq(const float* __restrict__ h,
                                            float* __restrict__ sq) {
    const int row = blockIdx.x;
    const int lane = threadIdx.x;
    float4 v = *(const float4*)&h[row * DOUT + lane * 4];
    float s = v.x * v.x + v.y * v.y + v.z * v.z + v.w * v.w;
#pragma unroll
    for (int off = 32; off; off >>= 1) s += __shfl_down(s, off);
    if (lane == 0) sq[row] = s;
}

// ---------------------------------------------------------------------------
// Kernel 3: MFMA Gram tile (128x128 per block) with fused masked max/min.
// mfma_f32_16x16x32_bf16; A frag: A[m=lane&15][k=(lane>>4)*8+j];
// C/D: col=lane&15, row=(lane>>4)*4+reg  (verified layouts).
// Writes per-j-block partials pmax/pmin [4096 x 32].
// ---------------------------------------------------------------------------
#define LDSTRIDE 72   // bf16 elems per LDS row (144 B: 16B-aligned, spreads banks)

__global__ __launch_bounds__(256) void hardest_mfma(
    const unsigned short* __restrict__ hb, const float* __restrict__ sq,
    const int* __restrict__ targets,
    float* __restrict__ pmax, float* __restrict__ pmin) {
    __shared__ __align__(16) short As[128 * LDSTRIDE];  // 18432 B
    __shared__ __align__(16) short Bs[128 * LDSTRIDE];  // 18432 B
    __shared__ int   tgtI[128];
    __shared__ int   tgtJ[128];
    __shared__ float sqJ[128];

    const int tid = threadIdx.x;
    const int w   = tid >> 6;        // wave 0..3 -> i-rows [w*32, w*32+32)
    const int l   = tid & 63;
    const int m16 = l & 15;
    const int q   = l >> 4;          // 0..3
    const int i0  = blockIdx.y * 128;
    const int j0  = blockIdx.x * 128;

    const int rS = tid >> 3;         // staging row 0..31 (+32*c)
    const int cS = (tid & 7) * 8;    // staging col (bf16 elems)

    ffrag acc[2][8] = {};            // [mi][nj]

    for (int kt = 0; kt < 4; ++kt) {
        const int k0 = kt * 64;
        uint4 av[4], bv[4];
#pragma unroll
        for (int c = 0; c < 4; ++c) {
            const int r = rS + 32 * c;
            av[c] = *(const uint4*)&hb[(size_t)(i0 + r) * DOUT + k0 + cS];
            bv[c] = *(const uint4*)&hb[(size_t)(j0 + r) * DOUT + k0 + cS];
        }
        __syncthreads();   // all waves done reading LDS from previous iter
#pragma unroll
        for (int c = 0; c < 4; ++c) {
            const int r = rS + 32 * c;
            *(uint4*)&As[r * LDSTRIDE + cS] = av[c];
            *(uint4*)&Bs[r * LDSTRIDE + cS] = bv[c];
        }
        if (kt == 0 && tid < 128) {
            tgtI[tid] = targets[i0 + tid];
            tgtJ[tid] = targets[j0 + tid];
            sqJ[tid]  = sq[j0 + tid];
        }
        __syncthreads();
#pragma unroll
        for (int s = 0; s < 2; ++s) {
            const int kl = s * 32 + q * 8;
            bfrag af[2];
#pragma unroll
            for (int mi = 0; mi < 2; ++mi)
                af[mi] = *(const bfrag*)&As[(w * 32 + mi * 16 + m16) * LDSTRIDE + kl];
#pragma unroll
            for (int nj = 0; nj < 8; ++nj) {
                bfrag bf = *(const bfrag*)&Bs[(nj * 16 + m16) * LDSTRIDE + kl];
#pragma unroll
                for (int mi = 0; mi < 2; ++mi)
                    acc[mi][nj] = __builtin_amdgcn_mfma_f32_16x16x32_bf16(
                        af[mi], bf, acc[mi][nj], 0, 0, 0);
            }
        }
    }

    // ---- fused epilogue: masked running max/min on (sq_j - 2*g) ----
    int ti[2][4];
#pragma unroll
    for (int mi = 0; mi < 2; ++mi)
#pragma unroll
        for (int reg = 0; reg < 4; ++reg)
            ti[mi][reg] = tgtI[w * 32 + mi * 16 + q * 4 + reg];

    float pmaxL[2][4], pminL[2][4];
#pragma unroll
    for (int mi = 0; mi < 2; ++mi)
#pragma unroll
        for (int reg = 0; reg < 4; ++reg) { pmaxL[mi][reg] = -INFINITY; pminL[mi][reg] = INFINITY; }

#pragma unroll
    for (int nj = 0; nj < 8; ++nj) {
        const int col = nj * 16 + m16;
        const float sv = sqJ[col];
        const int   tj = tgtJ[col];
#pragma unroll
        for (int mi = 0; mi < 2; ++mi)
#pragma unroll
            for (int reg = 0; reg < 4; ++reg) {
                const float v = fmaf(-2.0f, acc[mi][nj][reg], sv);
                if (ti[mi][reg] == tj) pmaxL[mi][reg] = fmaxf(pmaxL[mi][reg], v);
                else                   pminL[mi][reg] = fminf(pminL[mi][reg], v);
            }
    }

    // ---- cross-lane reduction via LDS (reuse As/Bs) ----
    __syncthreads();
    float* redmax = (float*)As;   // [128][17]
    float* redmin = (float*)Bs;
#pragma unroll
    for (int mi = 0; mi < 2; ++mi)
#pragma unroll
        for (int reg = 0; reg < 4; ++reg) {
            const int row = w * 32 + mi * 16 + q * 4 + reg;
            redmax[row * 17 + m16] = pmaxL[mi][reg];
            redmin[row * 17 + m16] = pminL[mi][reg];
        }
    __syncthreads();
    if (tid < 128) {
        float v = redmax[tid * 17];
        float u = redmin[tid * 17];
#pragma unroll
        for (int c = 1; c < 16; ++c) {
            v = fmaxf(v, redmax[tid * 17 + c]);
            u = fminf(u, redmin[tid * 17 + c]);
        }
        pmax[(size_t)(i0 + tid) * NCHUNK + blockIdx.x] = v;
        pmin[(size_t)(i0 + tid) * NCHUNK + blockIdx.x] = u;
    }
}

// ---------------------------------------------------------------------------
// Kernel 4: combine chunk partials, per-row loss, sum -> d_out[0]
// ---------------------------------------------------------------------------
__global__ __launch_bounds__(256) void finalize(const float* __restrict__ sq,
                                                const float* __restrict__ pmax,
                                                const float* __restrict__ pmin,
                                                float* __restrict__ out) {
    __shared__ float wsum[4];
    const int i = blockIdx.x * 256 + threadIdx.x;
    float mp = -INFINITY, mn = INFINITY;
#pragma unroll
    for (int c = 0; c < NCHUNK; ++c) {
        mp = fmaxf(mp, pmax[i * NCHUNK + c]);
        mn = fminf(mn, pmin[i * NCHUNK + c]);
    }
    const float si = sq[i];
    const float hp = sqrtf(fmaxf(si + mp, 0.0f));
    const float hn = sqrtf(fmaxf(si + mn, 0.0f));
    const float d  = hp - hn;
    float li = fmaxf(d, 0.0f) + log1pf(expf(-fabsf(d)));  // stable log1p(exp(d))
#pragma unroll
    for (int off = 32; off; off >>= 1) li += __shfl_down(li, off);
    const int lane = threadIdx.x & 63, wv = threadIdx.x >> 6;
    if (lane == 0) wsum[wv] = li;
    __syncthreads();
    if (threadIdx.x == 0)
        atomicAdd(out, wsum[0] + wsum[1] + wsum[2] + wsum[3]);
}

// ---------------------------------------------------------------------------
extern "C" void kernel_launch(void* const* d_in, const int* in_sizes, int n_in,
                              void* d_out, int out_size, void* d_ws, size_t ws_size,
                              hipStream_t stream) {
    const float* x       = (const float*)d_in[0];
    const float* W       = (const float*)d_in[1];
    const float* b       = (const float*)d_in[2];
    const int*   targets = (const int*)d_in[3];
    float* out = (float*)d_out;

    float*          h    = (float*)d_ws;                       // 4096*256 f32
    unsigned short* hb   = (unsigned short*)(h + NROWS * DOUT); // 4096*256 bf16
    float*          sq   = (float*)(hb + NROWS * DOUT);        // 4096
    float*          pmax = sq + NROWS;                         // 4096*32
    float*          pmin = pmax + NROWS * NCHUNK;              // 4096*32

    hipMemsetAsync(d_out, 0, sizeof(float), stream);

    gemm_xw<<<dim3(DOUT / 64, NROWS / 64), 256, 0, stream>>>(x, W, b, h, hb);
    rowsq<<<NROWS, 64, 0, stream>>>(h, sq);
    hardest_mfma<<<dim3(NCHUNK, NROWS / 128), 256, 0, stream>>>(hb, sq, targets, pmax, pmin);
    finalize<<<NROWS / 256, 256, 0, stream>>>(sq, pmax, pmin, out);
}

// Round 3
// 187.474 us; speedup vs baseline: 1.3710x; 1.0144x over previous
//
#include <hip/hip_runtime.h>
#include <math.h>

#define NROWS 4096
#define DIN   1024
#define DOUT  256
#define NCHUNK 32        // j-chunks (one 128-col block each) for the Gram kernel

using bfrag = __attribute__((ext_vector_type(8))) short;  // 8 bf16 (4 VGPRs)
using ffrag = __attribute__((ext_vector_type(4))) float;  // 4 fp32 acc

// round-to-nearest-even fp32 -> bf16 (values are finite; no NaN handling needed)
static __device__ __forceinline__ unsigned short f2bf(float f) {
    unsigned int u = __float_as_uint(f);
    u = (u + 0x7fffu + ((u >> 16) & 1u)) >> 16;
    return (unsigned short)u;
}
static __device__ __forceinline__ unsigned int pack2(float lo, float hi) {
    return (unsigned int)f2bf(lo) | ((unsigned int)f2bf(hi) << 16);
}

// ---------------------------------------------------------------------------
// Kernel 0: WbT[n][k] = bf16(W[k][n])  (transpose-convert, 1024x256 -> 256x1024)
// ---------------------------------------------------------------------------
__global__ __launch_bounds__(256) void wconv(const float* __restrict__ W,
                                             unsigned short* __restrict__ WbT) {
    __shared__ unsigned short T[32][33];
    const int t  = threadIdx.x;
    const int tx = t & 31, ty = t >> 5;          // 32 x 8
    const int n0 = blockIdx.x * 32;              // 0..224
    const int k0 = blockIdx.y * 32;              // 0..992
#pragma unroll
    for (int r = 0; r < 4; ++r) {
        const int k = ty + 8 * r;
        T[k][tx] = f2bf(W[(k0 + k) * DOUT + n0 + tx]);
    }
    __syncthreads();
#pragma unroll
    for (int r = 0; r < 4; ++r) {
        const int n = ty + 8 * r;
        WbT[(size_t)(n0 + n) * DIN + k0 + tx] = T[tx][n];
    }
}

// ---------------------------------------------------------------------------
// Kernel 1: h = x @ W + b via bf16 MFMA, fused sq + bf16 h output.
// BM=16, BN=256 (full width), BK=64. Grid = 256 blocks (NROWS/16).
// x converted fp32->bf16 inline during A staging (read exactly once).
// Outputs: hb (bf16 [4096][256]), sq (fp32 [4096]). No fp32 h materialized.
// ---------------------------------------------------------------------------
#define ASTRIDE 72
__global__ __launch_bounds__(256) void gemm1_mfma(
    const float* __restrict__ x, const unsigned short* __restrict__ WbT,
    const float* __restrict__ b,
    unsigned short* __restrict__ hb, float* __restrict__ sq) {
    __shared__ __align__(16) short As[16 * ASTRIDE];    //  2304 B
    __shared__ __align__(16) short Bs[256 * ASTRIDE];   // 36864 B

    const int tid = threadIdx.x;
    const int w   = tid >> 6;        // wave 0..3 -> col tiles [4w, 4w+4)
    const int l   = tid & 63;
    const int m16 = l & 15;
    const int q   = l >> 4;
    const int i0  = blockIdx.x * 16;

    // A staging map (threads 0..127): r = t>>3 (0..15), c = (t&7)*8
    const int rA = tid >> 3;
    const int cA = (tid & 7) * 8;
    // B staging map: 4 sweeps, n = s*64 + (t>>2), 16-elem chunk j16=(t&3)
    const int nB  = tid >> 2;
    const int j16 = (tid & 3) * 16;

    float4 a0, a1;
    uint4  bv[4][2];

#define G1_LOAD(KT)                                                          \
    {                                                                        \
        const int k0 = (KT) * 64;                                            \
        if (tid < 128) {                                                     \
            a0 = *(const float4*)&x[(size_t)(i0 + rA) * DIN + k0 + cA];      \
            a1 = *(const float4*)&x[(size_t)(i0 + rA) * DIN + k0 + cA + 4];  \
        }                                                                    \
        _Pragma("unroll")                                                    \
        for (int s = 0; s < 4; ++s) {                                        \
            const size_t base = (size_t)(s * 64 + nB) * DIN + k0 + j16;      \
            bv[s][0] = *(const uint4*)&WbT[base];                            \
            bv[s][1] = *(const uint4*)&WbT[base + 8];                        \
        }                                                                    \
    }

    ffrag acc[4] = {};

    G1_LOAD(0)
    for (int kt = 0; kt < 16; ++kt) {
        __syncthreads();
        if (tid < 128) {
            uint4 p;
            p.x = pack2(a0.x, a0.y);
            p.y = pack2(a0.z, a0.w);
            p.z = pack2(a1.x, a1.y);
            p.w = pack2(a1.z, a1.w);
            *(uint4*)&As[rA * ASTRIDE + cA] = p;
        }
#pragma unroll
        for (int s = 0; s < 4; ++s) {
            const int n = s * 64 + nB;
            *(uint4*)&Bs[n * ASTRIDE + j16]     = bv[s][0];
            *(uint4*)&Bs[n * ASTRIDE + j16 + 8] = bv[s][1];
        }
        __syncthreads();
        if (kt < 15) G1_LOAD(kt + 1)
#pragma unroll
        for (int s = 0; s < 2; ++s) {
            const int kl = s * 32 + q * 8;
            bfrag af = *(const bfrag*)&As[m16 * ASTRIDE + kl];
#pragma unroll
            for (int nj = 0; nj < 4; ++nj) {
                bfrag bf = *(const bfrag*)&Bs[((w * 4 + nj) * 16 + m16) * ASTRIDE + kl];
                acc[nj] = __builtin_amdgcn_mfma_f32_16x16x32_bf16(af, bf, acc[nj], 0, 0, 0);
            }
        }
    }
#undef G1_LOAD

    // ---- epilogue: bias, hb store, fused row-sq ----
    float bc[4];
#pragma unroll
    for (int nj = 0; nj < 4; ++nj) bc[nj] = b[(w * 4 + nj) * 16 + m16];

    float hv[4][4];
#pragma unroll
    for (int nj = 0; nj < 4; ++nj)
#pragma unroll
        for (int reg = 0; reg < 4; ++reg)
            hv[nj][reg] = acc[nj][reg] + bc[nj];

    // store hb (bf16)
#pragma unroll
    for (int reg = 0; reg < 4; ++reg) {
        const int r = q * 4 + reg;
#pragma unroll
        for (int nj = 0; nj < 4; ++nj)
            hb[(size_t)(i0 + r) * DOUT + (w * 4 + nj) * 16 + m16] = f2bf(hv[nj][reg]);
    }

    // row squared-norm: per lane partial over its 4 cols, per reg
    __syncthreads();  // done with As/Bs fragment reads; reuse As as float scratch
    float* sqred = (float*)As;   // [4 waves][16 rows]
#pragma unroll
    for (int reg = 0; reg < 4; ++reg) {
        float p = hv[0][reg] * hv[0][reg] + hv[1][reg] * hv[1][reg]
                + hv[2][reg] * hv[2][reg] + hv[3][reg] * hv[3][reg];
#pragma unroll
        for (int mask = 1; mask < 16; mask <<= 1) p += __shfl_xor(p, mask);
        if (m16 == 0) sqred[w * 16 + q * 4 + reg] = p;  // sum over wave's 64 cols
    }
    __syncthreads();
    if (tid < 16)
        sq[i0 + tid] = sqred[tid] + sqred[16 + tid] + sqred[32 + tid] + sqred[48 + tid];
}

// ---------------------------------------------------------------------------
// Kernel 2: MFMA Gram tile (128x128 per block) with fused masked max/min.
// ---------------------------------------------------------------------------
#define LDSTRIDE 72   // bf16 elems per LDS row

__global__ __launch_bounds__(256) void hardest_mfma(
    const unsigned short* __restrict__ hb, const float* __restrict__ sq,
    const int* __restrict__ targets,
    float* __restrict__ pmax, float* __restrict__ pmin) {
    __shared__ __align__(16) short As[128 * LDSTRIDE];  // 18432 B
    __shared__ __align__(16) short Bs[128 * LDSTRIDE];  // 18432 B
    __shared__ int   tgtI[128];
    __shared__ int   tgtJ[128];
    __shared__ float sqJ[128];

    const int tid = threadIdx.x;
    const int w   = tid >> 6;        // wave 0..3 -> i-rows [w*32, w*32+32)
    const int l   = tid & 63;
    const int m16 = l & 15;
    const int q   = l >> 4;          // 0..3
    const int i0  = blockIdx.y * 128;
    const int j0  = blockIdx.x * 128;

    const int rS = tid >> 3;         // staging row 0..31 (+32*c)
    const int cS = (tid & 7) * 8;    // staging col (bf16 elems)

    ffrag acc[2][8] = {};            // [mi][nj]
    uint4 av[4], bv[4];

#define GR_LOAD(KT)                                                          \
    {                                                                        \
        const int k0 = (KT) * 64;                                            \
        _Pragma("unroll")                                                    \
        for (int c = 0; c < 4; ++c) {                                        \
            const int r = rS + 32 * c;                                       \
            av[c] = *(const uint4*)&hb[(size_t)(i0 + r) * DOUT + k0 + cS];   \
            bv[c] = *(const uint4*)&hb[(size_t)(j0 + r) * DOUT + k0 + cS];   \
        }                                                                    \
    }

    GR_LOAD(0)
    for (int kt = 0; kt < 4; ++kt) {
        __syncthreads();   // all waves done reading LDS from previous iter
#pragma unroll
        for (int c = 0; c < 4; ++c) {
            const int r = rS + 32 * c;
            *(uint4*)&As[r * LDSTRIDE + cS] = av[c];
            *(uint4*)&Bs[r * LDSTRIDE + cS] = bv[c];
        }
        if (kt == 0 && tid < 128) {
            tgtI[tid] = targets[i0 + tid];
            tgtJ[tid] = targets[j0 + tid];
            sqJ[tid]  = sq[j0 + tid];
        }
        __syncthreads();
        if (kt < 3) GR_LOAD(kt + 1)
#pragma unroll
        for (int s = 0; s < 2; ++s) {
            const int kl = s * 32 + q * 8;
            bfrag af[2];
#pragma unroll
            for (int mi = 0; mi < 2; ++mi)
                af[mi] = *(const bfrag*)&As[(w * 32 + mi * 16 + m16) * LDSTRIDE + kl];
#pragma unroll
            for (int nj = 0; nj < 8; ++nj) {
                bfrag bf = *(const bfrag*)&Bs[(nj * 16 + m16) * LDSTRIDE + kl];
#pragma unroll
                for (int mi = 0; mi < 2; ++mi)
                    acc[mi][nj] = __builtin_amdgcn_mfma_f32_16x16x32_bf16(
                        af[mi], bf, acc[mi][nj], 0, 0, 0);
            }
        }
    }
#undef GR_LOAD

    // ---- fused epilogue: masked running max/min on (sq_j - 2*g) ----
    int ti[2][4];
#pragma unroll
    for (int mi = 0; mi < 2; ++mi)
#pragma unroll
        for (int reg = 0; reg < 4; ++reg)
            ti[mi][reg] = tgtI[w * 32 + mi * 16 + q * 4 + reg];

    float pmaxL[2][4], pminL[2][4];
#pragma unroll
    for (int mi = 0; mi < 2; ++mi)
#pragma unroll
        for (int reg = 0; reg < 4; ++reg) { pmaxL[mi][reg] = -INFINITY; pminL[mi][reg] = INFINITY; }

#pragma unroll
    for (int nj = 0; nj < 8; ++nj) {
        const int col = nj * 16 + m16;
        const float sv = sqJ[col];
        const int   tj = tgtJ[col];
#pragma unroll
        for (int mi = 0; mi < 2; ++mi)
#pragma unroll
            for (int reg = 0; reg < 4; ++reg) {
                const float v = fmaf(-2.0f, acc[mi][nj][reg], sv);
                if (ti[mi][reg] == tj) pmaxL[mi][reg] = fmaxf(pmaxL[mi][reg], v);
                else                   pminL[mi][reg] = fminf(pminL[mi][reg], v);
            }
    }

    // ---- cross-lane reduction via LDS (reuse As/Bs) ----
    __syncthreads();
    float* redmax = (float*)As;   // [128][17]
    float* redmin = (float*)Bs;
#pragma unroll
    for (int mi = 0; mi < 2; ++mi)
#pragma unroll
        for (int reg = 0; reg < 4; ++reg) {
            const int row = w * 32 + mi * 16 + q * 4 + reg;
            redmax[row * 17 + m16] = pmaxL[mi][reg];
            redmin[row * 17 + m16] = pminL[mi][reg];
        }
    __syncthreads();
    if (tid < 128) {
        float v = redmax[tid * 17];
        float u = redmin[tid * 17];
#pragma unroll
        for (int c = 1; c < 16; ++c) {
            v = fmaxf(v, redmax[tid * 17 + c]);
            u = fminf(u, redmin[tid * 17 + c]);
        }
        pmax[(size_t)(i0 + tid) * NCHUNK + blockIdx.x] = v;
        pmin[(size_t)(i0 + tid) * NCHUNK + blockIdx.x] = u;
    }
}

// ---------------------------------------------------------------------------
// Kernel 3: combine chunk partials, per-row loss, sum -> d_out[0]
// ---------------------------------------------------------------------------
__global__ __launch_bounds__(256) void finalize(const float* __restrict__ sq,
                                                const float* __restrict__ pmax,
                                                const float* __restrict__ pmin,
                                                float* __restrict__ out) {
    __shared__ float wsum[4];
    const int i = blockIdx.x * 256 + threadIdx.x;
    float mp = -INFINITY, mn = INFINITY;
#pragma unroll
    for (int c = 0; c < NCHUNK; ++c) {
        mp = fmaxf(mp, pmax[i * NCHUNK + c]);
        mn = fminf(mn, pmin[i * NCHUNK + c]);
    }
    const float si = sq[i];
    const float hp = sqrtf(fmaxf(si + mp, 0.0f));
    const float hn = sqrtf(fmaxf(si + mn, 0.0f));
    const float d  = hp - hn;
    float li = fmaxf(d, 0.0f) + log1pf(expf(-fabsf(d)));  // stable log1p(exp(d))
#pragma unroll
    for (int off = 32; off; off >>= 1) li += __shfl_down(li, off);
    const int lane = threadIdx.x & 63, wv = threadIdx.x >> 6;
    if (lane == 0) wsum[wv] = li;
    __syncthreads();
    if (threadIdx.x == 0)
        atomicAdd(out, wsum[0] + wsum[1] + wsum[2] + wsum[3]);
}

// ---------------------------------------------------------------------------
extern "C" void kernel_launch(void* const* d_in, const int* in_sizes, int n_in,
                              void* d_out, int out_size, void* d_ws, size_t ws_size,
                              hipStream_t stream) {
    const float* x       = (const float*)d_in[0];
    const float* W       = (const float*)d_in[1];
    const float* b       = (const float*)d_in[2];
    const int*   targets = (const int*)d_in[3];
    float* out = (float*)d_out;

    unsigned short* WbT  = (unsigned short*)d_ws;              // 256*1024 bf16
    unsigned short* hb   = WbT + DOUT * DIN;                   // 4096*256 bf16
    float*          sq   = (float*)(hb + NROWS * DOUT);        // 4096
    float*          pmax = sq + NROWS;                         // 4096*32
    float*          pmin = pmax + NROWS * NCHUNK;              // 4096*32

    hipMemsetAsync(d_out, 0, sizeof(float), stream);

    wconv<<<dim3(DOUT / 32, DIN / 32), 256, 0, stream>>>(W, WbT);
    gemm1_mfma<<<NROWS / 16, 256, 0, stream>>>(x, WbT, b, hb, sq);
    hardest_mfma<<<dim3(NCHUNK, NROWS / 128), 256, 0, stream>>>(hb, sq, targets, pmax, pmin);
    finalize<<<NROWS / 256, 256, 0, stream>>>(sq, pmax, pmin, out);
}

// Round 4
// 171.533 us; speedup vs baseline: 1.4984x; 1.0929x over previous
//
#include <hip/hip_runtime.h>
#include <math.h>

#define NROWS 4096
#define DIN   1024
#define DOUT  256
#define NCHUNK 32        // j-chunks (one 128-col block each) for the Gram kernel
#define NSQP  4          // sq partials (gemm1 j-chunks)

using bfrag = __attribute__((ext_vector_type(8))) short;  // 8 bf16 (4 VGPRs)
using ffrag = __attribute__((ext_vector_type(4))) float;  // 4 fp32 acc

// round-to-nearest-even fp32 -> bf16 (values are finite; no NaN handling needed)
static __device__ __forceinline__ unsigned short f2bf(float f) {
    unsigned int u = __float_as_uint(f);
    u = (u + 0x7fffu + ((u >> 16) & 1u)) >> 16;
    return (unsigned short)u;
}
static __device__ __forceinline__ unsigned int pack2(float lo, float hi) {
    return (unsigned int)f2bf(lo) | ((unsigned int)f2bf(hi) << 16);
}

// ---------------------------------------------------------------------------
// Kernel 0: WbT[n][k] = bf16(W[k][n])  (transpose-convert, 1024x256 -> 256x1024)
// ---------------------------------------------------------------------------
__global__ __launch_bounds__(256) void wconv(const float* __restrict__ W,
                                             unsigned short* __restrict__ WbT) {
    __shared__ unsigned short T[32][33];
    const int t  = threadIdx.x;
    const int tx = t & 31, ty = t >> 5;          // 32 x 8
    const int n0 = blockIdx.x * 32;
    const int k0 = blockIdx.y * 32;
#pragma unroll
    for (int r = 0; r < 4; ++r) {
        const int k = ty + 8 * r;
        T[k][tx] = f2bf(W[(k0 + k) * DOUT + n0 + tx]);
    }
    __syncthreads();
#pragma unroll
    for (int r = 0; r < 4; ++r) {
        const int n = ty + 8 * r;
        WbT[(size_t)(n0 + n) * DIN + k0 + tx] = T[tx][n];
    }
}

// ---------------------------------------------------------------------------
// Kernel 1: h = x @ W + b via bf16 MFMA. BM=16, BN=64, BK=64.
// Grid = (4 j-chunks, 256 i-blocks) = 1024 blocks -> 4 blocks/CU, 16 waves/CU.
// Wave w computes one 16x16 output tile (cols w*16..w*16+16 of the chunk).
// Outputs: hb (bf16 [4096][256]), sqp (fp32 [4][4096] transposed partials).
// ---------------------------------------------------------------------------
#define ASTRIDE 72
__global__ __launch_bounds__(256) void gemm1_mfma(
    const float* __restrict__ x, const unsigned short* __restrict__ WbT,
    const float* __restrict__ b,
    unsigned short* __restrict__ hb, float* __restrict__ sqp) {
    __shared__ __align__(16) short As[16 * ASTRIDE];    //  2304 B
    __shared__ __align__(16) short Bs[64 * ASTRIDE];    //  9216 B
    __shared__ float sqred[64];

    const int tid = threadIdx.x;
    const int w   = tid >> 6;        // wave 0..3 -> cols [w*16, w*16+16)
    const int l   = tid & 63;
    const int m16 = l & 15;
    const int q   = l >> 4;
    const int i0  = blockIdx.y * 16;
    const int n0  = blockIdx.x * 64;

    // A staging: r = tid>>4 (0..15), cA = (tid&15)*4 -> one float4 / thread
    const int rA = tid >> 4;
    const int cA = (tid & 15) * 4;
    // B staging: 2 sweeps of 32 rows; nB = tid>>3 (0..31), cB = (tid&7)*8
    const int nB = tid >> 3;
    const int cB = (tid & 7) * 8;

    float4 a4;
    uint4  bu[2];

#define G1_LOAD(KT)                                                           \
    {                                                                         \
        const int k0 = (KT) * 64;                                             \
        a4 = *(const float4*)&x[(size_t)(i0 + rA) * DIN + k0 + cA];           \
        bu[0] = *(const uint4*)&WbT[(size_t)(n0 + nB) * DIN + k0 + cB];       \
        bu[1] = *(const uint4*)&WbT[(size_t)(n0 + nB + 32) * DIN + k0 + cB];  \
    }

    ffrag acc = {};

    G1_LOAD(0)
    for (int kt = 0; kt < 16; ++kt) {
        __syncthreads();
        {
            uint2 p;
            p.x = pack2(a4.x, a4.y);
            p.y = pack2(a4.z, a4.w);
            *(uint2*)&As[rA * ASTRIDE + cA] = p;
            *(uint4*)&Bs[nB * ASTRIDE + cB]        = bu[0];
            *(uint4*)&Bs[(nB + 32) * ASTRIDE + cB] = bu[1];
        }
        __syncthreads();
        if (kt < 15) G1_LOAD(kt + 1)
#pragma unroll
        for (int s = 0; s < 2; ++s) {
            const int kl = s * 32 + q * 8;
            bfrag af = *(const bfrag*)&As[m16 * ASTRIDE + kl];
            bfrag bf = *(const bfrag*)&Bs[(w * 16 + m16) * ASTRIDE + kl];
            acc = __builtin_amdgcn_mfma_f32_16x16x32_bf16(af, bf, acc, 0, 0, 0);
        }
    }
#undef G1_LOAD

    // ---- epilogue: bias, hb store, fused partial row-sq ----
    const int col = n0 + w * 16 + m16;           // global output column
    const float bc = b[col];
    float hv[4];
#pragma unroll
    for (int reg = 0; reg < 4; ++reg) hv[reg] = acc[reg] + bc;

#pragma unroll
    for (int reg = 0; reg < 4; ++reg)
        hb[(size_t)(i0 + q * 4 + reg) * DOUT + col] = f2bf(hv[reg]);

    // rows q*4+reg: sum hv^2 over the wave's 16 cols (xor over m16 bits)
#pragma unroll
    for (int reg = 0; reg < 4; ++reg) {
        float p = hv[reg] * hv[reg];
#pragma unroll
        for (int mask = 1; mask < 16; mask <<= 1) p += __shfl_xor(p, mask);
        if (m16 == 0) sqred[w * 16 + q * 4 + reg] = p;
    }
    __syncthreads();
    if (tid < 16)
        sqp[blockIdx.x * NROWS + i0 + tid] =
            sqred[tid] + sqred[16 + tid] + sqred[32 + tid] + sqred[48 + tid];
}

// ---------------------------------------------------------------------------
// Kernel 2: MFMA Gram tile (128x128 per block) with fused masked max/min.
// Partials written transposed: pmax/pmin [NCHUNK][4096] (coalesced).
// ---------------------------------------------------------------------------
#define LDSTRIDE 72   // bf16 elems per LDS row

__global__ __launch_bounds__(256) void hardest_mfma(
    const unsigned short* __restrict__ hb, const float* __restrict__ sqp,
    const int* __restrict__ targets,
    float* __restrict__ pmax, float* __restrict__ pmin) {
    __shared__ __align__(16) short As[128 * LDSTRIDE];  // 18432 B
    __shared__ __align__(16) short Bs[128 * LDSTRIDE];  // 18432 B
    __shared__ int   tgtI[128];
    __shared__ int   tgtJ[128];
    __shared__ float sqJ[128];

    const int tid = threadIdx.x;
    const int w   = tid >> 6;        // wave 0..3 -> i-rows [w*32, w*32+32)
    const int l   = tid & 63;
    const int m16 = l & 15;
    const int q   = l >> 4;          // 0..3
    const int i0  = blockIdx.y * 128;
    const int j0  = blockIdx.x * 128;

    const int rS = tid >> 3;         // staging row 0..31 (+32*c)
    const int cS = (tid & 7) * 8;    // staging col (bf16 elems)

    ffrag acc[2][8] = {};            // [mi][nj]
    uint4 av[4], bv[4];

#define GR_LOAD(KT)                                                          \
    {                                                                        \
        const int k0 = (KT) * 64;                                            \
        _Pragma("unroll")                                                    \
        for (int c = 0; c < 4; ++c) {                                        \
            const int r = rS + 32 * c;                                       \
            av[c] = *(const uint4*)&hb[(size_t)(i0 + r) * DOUT + k0 + cS];   \
            bv[c] = *(const uint4*)&hb[(size_t)(j0 + r) * DOUT + k0 + cS];   \
        }                                                                    \
    }

    GR_LOAD(0)
    for (int kt = 0; kt < 4; ++kt) {
        __syncthreads();   // all waves done reading LDS from previous iter
#pragma unroll
        for (int c = 0; c < 4; ++c) {
            const int r = rS + 32 * c;
            *(uint4*)&As[r * LDSTRIDE + cS] = av[c];
            *(uint4*)&Bs[r * LDSTRIDE + cS] = bv[c];
        }
        if (kt == 0 && tid < 128) {
            tgtI[tid] = targets[i0 + tid];
            tgtJ[tid] = targets[j0 + tid];
            const int j = j0 + tid;
            sqJ[tid] = sqp[j] + sqp[NROWS + j] + sqp[2 * NROWS + j] + sqp[3 * NROWS + j];
        }
        __syncthreads();
        if (kt < 3) GR_LOAD(kt + 1)
#pragma unroll
        for (int s = 0; s < 2; ++s) {
            const int kl = s * 32 + q * 8;
            bfrag af[2];
#pragma unroll
            for (int mi = 0; mi < 2; ++mi)
                af[mi] = *(const bfrag*)&As[(w * 32 + mi * 16 + m16) * LDSTRIDE + kl];
#pragma unroll
            for (int nj = 0; nj < 8; ++nj) {
                bfrag bf = *(const bfrag*)&Bs[(nj * 16 + m16) * LDSTRIDE + kl];
#pragma unroll
                for (int mi = 0; mi < 2; ++mi)
                    acc[mi][nj] = __builtin_amdgcn_mfma_f32_16x16x32_bf16(
                        af[mi], bf, acc[mi][nj], 0, 0, 0);
            }
        }
    }
#undef GR_LOAD

    // ---- fused epilogue: masked running max/min on (sq_j - 2*g) ----
    int ti[2][4];
#pragma unroll
    for (int mi = 0; mi < 2; ++mi)
#pragma unroll
        for (int reg = 0; reg < 4; ++reg)
            ti[mi][reg] = tgtI[w * 32 + mi * 16 + q * 4 + reg];

    float pmaxL[2][4], pminL[2][4];
#pragma unroll
    for (int mi = 0; mi < 2; ++mi)
#pragma unroll
        for (int reg = 0; reg < 4; ++reg) { pmaxL[mi][reg] = -INFINITY; pminL[mi][reg] = INFINITY; }

#pragma unroll
    for (int nj = 0; nj < 8; ++nj) {
        const int col = nj * 16 + m16;
        const float sv = sqJ[col];
        const int   tj = tgtJ[col];
#pragma unroll
        for (int mi = 0; mi < 2; ++mi)
#pragma unroll
            for (int reg = 0; reg < 4; ++reg) {
                const float v = fmaf(-2.0f, acc[mi][nj][reg], sv);
                if (ti[mi][reg] == tj) pmaxL[mi][reg] = fmaxf(pmaxL[mi][reg], v);
                else                   pminL[mi][reg] = fminf(pminL[mi][reg], v);
            }
    }

    // ---- cross-lane reduction via LDS (reuse As/Bs) ----
    __syncthreads();
    float* redmax = (float*)As;   // [128][17]
    float* redmin = (float*)Bs;
#pragma unroll
    for (int mi = 0; mi < 2; ++mi)
#pragma unroll
        for (int reg = 0; reg < 4; ++reg) {
            const int row = w * 32 + mi * 16 + q * 4 + reg;
            redmax[row * 17 + m16] = pmaxL[mi][reg];
            redmin[row * 17 + m16] = pminL[mi][reg];
        }
    __syncthreads();
    if (tid < 128) {
        float v = redmax[tid * 17];
        float u = redmin[tid * 17];
#pragma unroll
        for (int c = 1; c < 16; ++c) {
            v = fmaxf(v, redmax[tid * 17 + c]);
            u = fminf(u, redmin[tid * 17 + c]);
        }
        pmax[(size_t)blockIdx.x * NROWS + i0 + tid] = v;   // coalesced
        pmin[(size_t)blockIdx.x * NROWS + i0 + tid] = u;
    }
}

// ---------------------------------------------------------------------------
// Kernel 3: combine chunk partials, per-row loss, sum -> d_out[0]
// All loads coalesced (partials are [chunk][4096]).
// ---------------------------------------------------------------------------
__global__ __launch_bounds__(256) void finalize(const float* __restrict__ sqp,
                                                const float* __restrict__ pmax,
                                                const float* __restrict__ pmin,
                                                float* __restrict__ out) {
    __shared__ float wsum[4];
    const int i = blockIdx.x * 256 + threadIdx.x;
    float mp = -INFINITY, mn = INFINITY;
#pragma unroll
    for (int c = 0; c < NCHUNK; ++c) {
        mp = fmaxf(mp, pmax[c * NROWS + i]);
        mn = fminf(mn, pmin[c * NROWS + i]);
    }
    const float si = sqp[i] + sqp[NROWS + i] + sqp[2 * NROWS + i] + sqp[3 * NROWS + i];
    const float hp = sqrtf(fmaxf(si + mp, 0.0f));
    const float hn = sqrtf(fmaxf(si + mn, 0.0f));
    const float d  = hp - hn;
    float li = fmaxf(d, 0.0f) + log1pf(expf(-fabsf(d)));  // stable log1p(exp(d))
#pragma unroll
    for (int off = 32; off; off >>= 1) li += __shfl_down(li, off);
    const int lane = threadIdx.x & 63, wv = threadIdx.x >> 6;
    if (lane == 0) wsum[wv] = li;
    __syncthreads();
    if (threadIdx.x == 0)
        atomicAdd(out, wsum[0] + wsum[1] + wsum[2] + wsum[3]);
}

// ---------------------------------------------------------------------------
extern "C" void kernel_launch(void* const* d_in, const int* in_sizes, int n_in,
                              void* d_out, int out_size, void* d_ws, size_t ws_size,
                              hipStream_t stream) {
    const float* x       = (const float*)d_in[0];
    const float* W       = (const float*)d_in[1];
    const float* b       = (const float*)d_in[2];
    const int*   targets = (const int*)d_in[3];
    float* out = (float*)d_out;

    unsigned short* WbT  = (unsigned short*)d_ws;               // 256*1024 bf16
    unsigned short* hb   = WbT + DOUT * DIN;                    // 4096*256 bf16
    float*          sqp  = (float*)(hb + NROWS * DOUT);         // [4][4096]
    float*          pmax = sqp + NSQP * NROWS;                  // [32][4096]
    float*          pmin = pmax + NCHUNK * NROWS;               // [32][4096]

    hipMemsetAsync(d_out, 0, sizeof(float), stream);

    wconv<<<dim3(DOUT / 32, DIN / 32), 256, 0, stream>>>(W, WbT);
    gemm1_mfma<<<dim3(NSQP, NROWS / 16), 256, 0, stream>>>(x, WbT, b, hb, sqp);
    hardest_mfma<<<dim3(NCHUNK, NROWS / 128), 256, 0, stream>>>(hb, sqp, targets, pmax, pmin);
    finalize<<<NROWS / 256, 256, 0, stream>>>(sqp, pmax, pmin, out);
}

// Round 5
// 170.500 us; speedup vs baseline: 1.5075x; 1.0061x over previous
//
#include <hip/hip_runtime.h>
#include <math.h>

#define NROWS 4096
#define DIN   1024
#define DOUT  256
#define NJB   64         // j-blocks for the Gram kernel (64 cols each)
#define NSQP  4          // sq partials (gemm1 j-chunks)

using bfrag = __attribute__((ext_vector_type(8))) short;  // 8 bf16 (4 VGPRs)
using ffrag = __attribute__((ext_vector_type(4))) float;  // 4 fp32 acc

// round-to-nearest-even fp32 -> bf16 (values are finite; no NaN handling needed)
static __device__ __forceinline__ unsigned short f2bf(float f) {
    unsigned int u = __float_as_uint(f);
    u = (u + 0x7fffu + ((u >> 16) & 1u)) >> 16;
    return (unsigned short)u;
}
static __device__ __forceinline__ unsigned int pack2(float lo, float hi) {
    return (unsigned int)f2bf(lo) | ((unsigned int)f2bf(hi) << 16);
}

// ---------------------------------------------------------------------------
// Kernel 0: WbT[n][k] = bf16(W[k][n])  (transpose-convert, 1024x256 -> 256x1024)
// ---------------------------------------------------------------------------
__global__ __launch_bounds__(256) void wconv(const float* __restrict__ W,
                                             unsigned short* __restrict__ WbT) {
    __shared__ unsigned short T[32][33];
    const int t  = threadIdx.x;
    const int tx = t & 31, ty = t >> 5;          // 32 x 8
    const int n0 = blockIdx.x * 32;
    const int k0 = blockIdx.y * 32;
#pragma unroll
    for (int r = 0; r < 4; ++r) {
        const int k = ty + 8 * r;
        T[k][tx] = f2bf(W[(k0 + k) * DOUT + n0 + tx]);
    }
    __syncthreads();
#pragma unroll
    for (int r = 0; r < 4; ++r) {
        const int n = ty + 8 * r;
        WbT[(size_t)(n0 + n) * DIN + k0 + tx] = T[tx][n];
    }
}

// ---------------------------------------------------------------------------
// Kernel 1: h = x @ W + b via bf16 MFMA. BM=16, BN=64, BK=64.
// Grid = (4 j-chunks, 256 i-blocks) = 1024 blocks -> 4 blocks/CU, 16 waves/CU.
// Outputs: hb (bf16 [4096][256]), sqp (fp32 [4][4096] transposed partials).
// ---------------------------------------------------------------------------
#define ASTRIDE 72
__global__ __launch_bounds__(256) void gemm1_mfma(
    const float* __restrict__ x, const unsigned short* __restrict__ WbT,
    const float* __restrict__ b,
    unsigned short* __restrict__ hb, float* __restrict__ sqp) {
    __shared__ __align__(16) short As[16 * ASTRIDE];    //  2304 B
    __shared__ __align__(16) short Bs[64 * ASTRIDE];    //  9216 B
    __shared__ float sqred[64];

    const int tid = threadIdx.x;
    const int w   = tid >> 6;        // wave 0..3 -> cols [w*16, w*16+16)
    const int l   = tid & 63;
    const int m16 = l & 15;
    const int q   = l >> 4;
    const int i0  = blockIdx.y * 16;
    const int n0  = blockIdx.x * 64;

    const int rA = tid >> 4;
    const int cA = (tid & 15) * 4;
    const int nB = tid >> 3;
    const int cB = (tid & 7) * 8;

    float4 a4;
    uint4  bu[2];

#define G1_LOAD(KT)                                                           \
    {                                                                         \
        const int k0 = (KT) * 64;                                             \
        a4 = *(const float4*)&x[(size_t)(i0 + rA) * DIN + k0 + cA];           \
        bu[0] = *(const uint4*)&WbT[(size_t)(n0 + nB) * DIN + k0 + cB];       \
        bu[1] = *(const uint4*)&WbT[(size_t)(n0 + nB + 32) * DIN + k0 + cB];  \
    }

    ffrag acc = {};

    G1_LOAD(0)
    for (int kt = 0; kt < 16; ++kt) {
        __syncthreads();
        {
            uint2 p;
            p.x = pack2(a4.x, a4.y);
            p.y = pack2(a4.z, a4.w);
            *(uint2*)&As[rA * ASTRIDE + cA] = p;
            *(uint4*)&Bs[nB * ASTRIDE + cB]        = bu[0];
            *(uint4*)&Bs[(nB + 32) * ASTRIDE + cB] = bu[1];
        }
        __syncthreads();
        if (kt < 15) G1_LOAD(kt + 1)
#pragma unroll
        for (int s = 0; s < 2; ++s) {
            const int kl = s * 32 + q * 8;
            bfrag af = *(const bfrag*)&As[m16 * ASTRIDE + kl];
            bfrag bf = *(const bfrag*)&Bs[(w * 16 + m16) * ASTRIDE + kl];
            acc = __builtin_amdgcn_mfma_f32_16x16x32_bf16(af, bf, acc, 0, 0, 0);
        }
    }
#undef G1_LOAD

    // ---- epilogue: bias, hb store, fused partial row-sq ----
    const int col = n0 + w * 16 + m16;           // global output column
    const float bc = b[col];
    float hv[4];
#pragma unroll
    for (int reg = 0; reg < 4; ++reg) hv[reg] = acc[reg] + bc;

#pragma unroll
    for (int reg = 0; reg < 4; ++reg)
        hb[(size_t)(i0 + q * 4 + reg) * DOUT + col] = f2bf(hv[reg]);

#pragma unroll
    for (int reg = 0; reg < 4; ++reg) {
        float p = hv[reg] * hv[reg];
#pragma unroll
        for (int mask = 1; mask < 16; mask <<= 1) p += __shfl_xor(p, mask);
        if (m16 == 0) sqred[w * 16 + q * 4 + reg] = p;
    }
    __syncthreads();
    if (tid < 16)
        sqp[blockIdx.x * NROWS + i0 + tid] =
            sqred[tid] + sqred[16 + tid] + sqred[32 + tid] + sqred[48 + tid];
}

// ---------------------------------------------------------------------------
// Kernel 2: register-direct Gram + fused masked max/min. NO LDS, NO barriers.
// hb is row-major so every MFMA A/B fragment is a contiguous 16B run of one
// row: load fragments straight from global (hb is 2MB -> L2-resident).
// Block = 128 i-rows (4 waves x 32) x 64 j-cols; grid (64 j, 32 i) = 2048.
// Per wave: 8 ks x (2 A-frag + 4 B-frag loads, 8 MFMAs) -> 48 loads, 64 MFMA,
// fully vmcnt-pipelineable with zero __syncthreads in the loop.
// Partials pmax/pmin [NJB][4096] (coalesced-ish scalar stores, 1MB each).
// ---------------------------------------------------------------------------
__global__ __launch_bounds__(256) void hardest_reg(
    const unsigned short* __restrict__ hb, const float* __restrict__ sqp,
    const int* __restrict__ targets,
    float* __restrict__ pmax, float* __restrict__ pmin) {
    const int tid = threadIdx.x;
    const int w   = tid >> 6;        // wave 0..3 -> i-rows [w*32, w*32+32)
    const int l   = tid & 63;
    const int m16 = l & 15;
    const int q   = l >> 4;          // 0..3
    const int i0  = blockIdx.y * 128;
    const int j0  = blockIdx.x * 64;
    const int iw  = i0 + w * 32;

    const unsigned short* A0 = hb + (size_t)(iw + m16) * DOUT;
    const unsigned short* A1 = hb + (size_t)(iw + 16 + m16) * DOUT;
    const unsigned short* B0 = hb + (size_t)(j0 + m16) * DOUT;

    ffrag acc[2][4] = {};            // [mi][nj]

#pragma unroll
    for (int ks = 0; ks < 8; ++ks) {
        const int kk = ks * 32 + q * 8;
        bfrag a0 = *(const bfrag*)(A0 + kk);
        bfrag a1 = *(const bfrag*)(A1 + kk);
#pragma unroll
        for (int nj = 0; nj < 4; ++nj) {
            bfrag bf = *(const bfrag*)(B0 + (size_t)(nj * 16) * DOUT + kk);
            acc[0][nj] = __builtin_amdgcn_mfma_f32_16x16x32_bf16(a0, bf, acc[0][nj], 0, 0, 0);
            acc[1][nj] = __builtin_amdgcn_mfma_f32_16x16x32_bf16(a1, bf, acc[1][nj], 0, 0, 0);
        }
    }

    // ---- fused epilogue: masked running max/min on (sq_j - 2*g) ----
    int   tj[4];
    float sv[4];
#pragma unroll
    for (int nj = 0; nj < 4; ++nj) {
        const int col = j0 + nj * 16 + m16;
        tj[nj] = targets[col];
        sv[nj] = sqp[col] + sqp[NROWS + col] + sqp[2 * NROWS + col] + sqp[3 * NROWS + col];
    }

#pragma unroll
    for (int mi = 0; mi < 2; ++mi)
#pragma unroll
        for (int reg = 0; reg < 4; ++reg) {
            const int row = iw + mi * 16 + q * 4 + reg;
            const int ti  = targets[row];     // same addr across m16-group: broadcast
            float mx = -INFINITY, mn = INFINITY;
#pragma unroll
            for (int nj = 0; nj < 4; ++nj) {
                const float v = fmaf(-2.0f, acc[mi][nj][reg], sv[nj]);
                if (tj[nj] == ti) mx = fmaxf(mx, v);
                else              mn = fminf(mn, v);
            }
            // reduce over the 16 m16-lanes (same q): xor masks 1,2,4,8
#pragma unroll
            for (int mask = 1; mask < 16; mask <<= 1) {
                mx = fmaxf(mx, __shfl_xor(mx, mask));
                mn = fminf(mn, __shfl_xor(mn, mask));
            }
            if (m16 == 0) {
                pmax[(size_t)blockIdx.x * NROWS + row] = mx;
                pmin[(size_t)blockIdx.x * NROWS + row] = mn;
            }
        }
}

// ---------------------------------------------------------------------------
// Kernel 3: combine chunk partials, per-row loss, sum -> d_out[0]
// ---------------------------------------------------------------------------
__global__ __launch_bounds__(256) void finalize(const float* __restrict__ sqp,
                                                const float* __restrict__ pmax,
                                                const float* __restrict__ pmin,
                                                float* __restrict__ out) {
    __shared__ float wsum[4];
    const int i = blockIdx.x * 256 + threadIdx.x;
    float mp = -INFINITY, mn = INFINITY;
#pragma unroll
    for (int c = 0; c < NJB; ++c) {
        mp = fmaxf(mp, pmax[c * NROWS + i]);
        mn = fminf(mn, pmin[c * NROWS + i]);
    }
    const float si = sqp[i] + sqp[NROWS + i] + sqp[2 * NROWS + i] + sqp[3 * NROWS + i];
    const float hp = sqrtf(fmaxf(si + mp, 0.0f));
    const float hn = sqrtf(fmaxf(si + mn, 0.0f));
    const float d  = hp - hn;
    float li = fmaxf(d, 0.0f) + log1pf(expf(-fabsf(d)));  // stable log1p(exp(d))
#pragma unroll
    for (int off = 32; off; off >>= 1) li += __shfl_down(li, off);
    const int lane = threadIdx.x & 63, wv = threadIdx.x >> 6;
    if (lane == 0) wsum[wv] = li;
    __syncthreads();
    if (threadIdx.x == 0)
        atomicAdd(out, wsum[0] + wsum[1] + wsum[2] + wsum[3]);
}

// ---------------------------------------------------------------------------
extern "C" void kernel_launch(void* const* d_in, const int* in_sizes, int n_in,
                              void* d_out, int out_size, void* d_ws, size_t ws_size,
                              hipStream_t stream) {
    const float* x       = (const float*)d_in[0];
    const float* W       = (const float*)d_in[1];
    const float* b       = (const float*)d_in[2];
    const int*   targets = (const int*)d_in[3];
    float* out = (float*)d_out;

    unsigned short* WbT  = (unsigned short*)d_ws;               // 256*1024 bf16
    unsigned short* hb   = WbT + DOUT * DIN;                    // 4096*256 bf16
    float*          sqp  = (float*)(hb + NROWS * DOUT);         // [4][4096]
    float*          pmax = sqp + NSQP * NROWS;                  // [64][4096]
    float*          pmin = pmax + NJB * NROWS;                  // [64][4096]

    hipMemsetAsync(d_out, 0, sizeof(float), stream);

    wconv<<<dim3(DOUT / 32, DIN / 32), 256, 0, stream>>>(W, WbT);
    gemm1_mfma<<<dim3(NSQP, NROWS / 16), 256, 0, stream>>>(x, WbT, b, hb, sqp);
    hardest_reg<<<dim3(NJB, NROWS / 128), 256, 0, stream>>>(hb, sqp, targets, pmax, pmin);
    finalize<<<NROWS / 256, 256, 0, stream>>>(sqp, pmax, pmin, out);
}

// Round 6
// 142.927 us; speedup vs baseline: 1.7983x; 1.1929x over previous
//
#include <hip/hip_runtime.h>
#include <math.h>

#define NROWS 4096
#define DIN   1024
#define DOUT  256
#define NJB   64         // 64-col j-chunks for partials
#define NSQP  4          // sq partials (gemm1 j-chunks)

using bfrag = __attribute__((ext_vector_type(8))) short;  // 8 bf16 (4 VGPRs)
using ffrag = __attribute__((ext_vector_type(4))) float;  // 4 fp32 acc

// hs layout: fragment-order h. hs[t][ks][l][j] = h[t*16 + (l&15)][ks*32 + (l>>4)*8 + j]
// -> one MFMA A/B fragment for (t,ks) is the 16B at hs + ((t*8+ks)*64 + l)*8.
// A- and B-fragments of mfma_f32_16x16x32_bf16 share this per-lane map, so one
// buffer serves both sides of the Gram (g = h h^T).

static __device__ __forceinline__ unsigned short f2bf(float f) {
    unsigned int u = __float_as_uint(f);
    u = (u + 0x7fffu + ((u >> 16) & 1u)) >> 16;
    return (unsigned short)u;
}
static __device__ __forceinline__ unsigned int pack2(float lo, float hi) {
    return (unsigned int)f2bf(lo) | ((unsigned int)f2bf(hi) << 16);
}

// ---------------------------------------------------------------------------
// Kernel 0: WbT[n][k] = bf16(W[k][n])  (transpose-convert)
// ---------------------------------------------------------------------------
__global__ __launch_bounds__(256) void wconv(const float* __restrict__ W,
                                             unsigned short* __restrict__ WbT) {
    __shared__ unsigned short T[32][33];
    const int t  = threadIdx.x;
    const int tx = t & 31, ty = t >> 5;          // 32 x 8
    const int n0 = blockIdx.x * 32;
    const int k0 = blockIdx.y * 32;
#pragma unroll
    for (int r = 0; r < 4; ++r) {
        const int k = ty + 8 * r;
        T[k][tx] = f2bf(W[(k0 + k) * DOUT + n0 + tx]);
    }
    __syncthreads();
#pragma unroll
    for (int r = 0; r < 4; ++r) {
        const int n = ty + 8 * r;
        WbT[(size_t)(n0 + n) * DIN + k0 + tx] = T[tx][n];
    }
}

// ---------------------------------------------------------------------------
// Kernel 1: h = x @ W + b via bf16 MFMA. BM=16, BN=64, BK=64. Grid (4,256).
// Epilogue: LDS transpose -> hs written in fragment order (16B coalesced),
// fused partial row-sq.  No plain h / hb materialized at all.
// ---------------------------------------------------------------------------
#define ASTRIDE 72
#define HTSTRIDE 80   // shorts; 160B rows keep 16B alignment for b128 reads
__global__ __launch_bounds__(256) void gemm1_mfma(
    const float* __restrict__ x, const unsigned short* __restrict__ WbT,
    const float* __restrict__ b,
    unsigned short* __restrict__ hs, float* __restrict__ sqp) {
    __shared__ __align__(16) short As[16 * ASTRIDE];    //  2304 B
    __shared__ __align__(16) short Bs[64 * ASTRIDE];    //  9216 B
    __shared__ __align__(16) short Ht[16 * HTSTRIDE];   //  2560 B
    __shared__ float sqred[64];

    const int tid = threadIdx.x;
    const int w   = tid >> 6;        // wave 0..3 -> cols [w*16, w*16+16)
    const int l   = tid & 63;
    const int m16 = l & 15;
    const int q   = l >> 4;
    const int i0  = blockIdx.y * 16;
    const int n0  = blockIdx.x * 64;

    const int rA = tid >> 4;
    const int cA = (tid & 15) * 4;
    const int nB = tid >> 3;
    const int cB = (tid & 7) * 8;

    float4 a4;
    uint4  bu[2];

#define G1_LOAD(KT)                                                           \
    {                                                                         \
        const int k0 = (KT) * 64;                                             \
        a4 = *(const float4*)&x[(size_t)(i0 + rA) * DIN + k0 + cA];           \
        bu[0] = *(const uint4*)&WbT[(size_t)(n0 + nB) * DIN + k0 + cB];       \
        bu[1] = *(const uint4*)&WbT[(size_t)(n0 + nB + 32) * DIN + k0 + cB];  \
    }

    ffrag acc = {};

    G1_LOAD(0)
    for (int kt = 0; kt < 16; ++kt) {
        __syncthreads();
        {
            uint2 p;
            p.x = pack2(a4.x, a4.y);
            p.y = pack2(a4.z, a4.w);
            *(uint2*)&As[rA * ASTRIDE + cA] = p;
            *(uint4*)&Bs[nB * ASTRIDE + cB]        = bu[0];
            *(uint4*)&Bs[(nB + 32) * ASTRIDE + cB] = bu[1];
        }
        __syncthreads();
        if (kt < 15) G1_LOAD(kt + 1)
#pragma unroll
        for (int s = 0; s < 2; ++s) {
            const int kl = s * 32 + q * 8;
            bfrag af = *(const bfrag*)&As[m16 * ASTRIDE + kl];
            bfrag bf = *(const bfrag*)&Bs[(w * 16 + m16) * ASTRIDE + kl];
            acc = __builtin_amdgcn_mfma_f32_16x16x32_bf16(af, bf, acc, 0, 0, 0);
        }
    }
#undef G1_LOAD

    // ---- epilogue: bias, LDS transpose to fragment order, fused row-sq ----
    const int col = w * 16 + m16;                // block-local output column
    const float bc = b[n0 + col];
    float hv[4];
#pragma unroll
    for (int reg = 0; reg < 4; ++reg) hv[reg] = acc[reg] + bc;

    __syncthreads();   // all waves done with As/Bs fragment reads
#pragma unroll
    for (int reg = 0; reg < 4; ++reg)
        Ht[(q * 4 + reg) * HTSTRIDE + col] = f2bf(hv[reg]);   // Ht[row16][col64]

#pragma unroll
    for (int reg = 0; reg < 4; ++reg) {
        float p = hv[reg] * hv[reg];
#pragma unroll
        for (int mask = 1; mask < 16; mask <<= 1) p += __shfl_xor(p, mask);
        if (m16 == 0) sqred[w * 16 + q * 4 + reg] = p;
    }
    __syncthreads();
    if (tid < 128) {
        const int c2 = tid >> 6;                 // ks within block (0..1)
        const int ll = tid & 63;
        bfrag v = *(const bfrag*)&Ht[(ll & 15) * HTSTRIDE + c2 * 32 + (ll >> 4) * 8];
        const size_t idx = ((size_t)(blockIdx.y * 8 + blockIdx.x * 2 + c2) * 64 + ll) * 8;
        *(bfrag*)&hs[idx] = v;                   // 16B coalesced fragment store
    }
    if (tid < 16)
        sqp[blockIdx.x * NROWS + i0 + tid] =
            sqred[tid] + sqred[16 + tid] + sqred[32 + tid] + sqred[48 + tid];
}

// ---------------------------------------------------------------------------
// Kernel 2: register-direct Gram from fragment-order hs. No LDS, no barriers.
// Block = 128i x 128j; 4 waves in 2x2, each wave a 64x64 tile:
// 4 A-frags x 4 B-frags x 16 MFMAs per ks, all loads lane-contiguous 1KB.
// Fused masked max/min on (sq_j - 2g); partials [NJB=64][4096].
// ---------------------------------------------------------------------------
__global__ __launch_bounds__(256) void hardest_reg(
    const unsigned short* __restrict__ hs, const float* __restrict__ sqp,
    const int* __restrict__ targets,
    float* __restrict__ pmax, float* __restrict__ pmin) {
    const int tid = threadIdx.x;
    const int w   = tid >> 6;
    const int wi  = w & 1, wj = w >> 1;
    const int l   = tid & 63;
    const int m16 = l & 15;
    const int q   = l >> 4;
    const int i0  = blockIdx.y * 128;
    const int j0  = blockIdx.x * 128;
    const int iw  = i0 + wi * 64;
    const int jw  = j0 + wj * 64;
    const int tA  = iw >> 4;                     // row-tile indices (4 of them)
    const int tB  = jw >> 4;

    ffrag acc[4][4] = {};                        // [mi][nj]

#pragma unroll
    for (int ks = 0; ks < 8; ++ks) {
        bfrag a[4], bb[4];
#pragma unroll
        for (int mi = 0; mi < 4; ++mi)
            a[mi] = *(const bfrag*)&hs[(((size_t)(tA + mi) * 8 + ks) * 64 + l) * 8];
#pragma unroll
        for (int nj = 0; nj < 4; ++nj)
            bb[nj] = *(const bfrag*)&hs[(((size_t)(tB + nj) * 8 + ks) * 64 + l) * 8];
#pragma unroll
        for (int mi = 0; mi < 4; ++mi)
#pragma unroll
            for (int nj = 0; nj < 4; ++nj)
                acc[mi][nj] = __builtin_amdgcn_mfma_f32_16x16x32_bf16(
                    a[mi], bb[nj], acc[mi][nj], 0, 0, 0);
    }

    // ---- fused epilogue: masked running max/min on (sq_j - 2*g) ----
    int   tj[4];
    float sv[4];
#pragma unroll
    for (int nj = 0; nj < 4; ++nj) {
        const int col = jw + nj * 16 + m16;
        tj[nj] = targets[col];
        sv[nj] = sqp[col] + sqp[NROWS + col] + sqp[2 * NROWS + col] + sqp[3 * NROWS + col];
    }

    const int jblk = blockIdx.x * 2 + wj;        // 64-col chunk index (0..63)
#pragma unroll
    for (int mi = 0; mi < 4; ++mi)
#pragma unroll
        for (int reg = 0; reg < 4; ++reg) {
            const int row = iw + mi * 16 + q * 4 + reg;
            const int ti  = targets[row];
            float mx = -INFINITY, mn = INFINITY;
#pragma unroll
            for (int nj = 0; nj < 4; ++nj) {
                const float v = fmaf(-2.0f, acc[mi][nj][reg], sv[nj]);
                if (tj[nj] == ti) mx = fmaxf(mx, v);
                else              mn = fminf(mn, v);
            }
#pragma unroll
            for (int mask = 1; mask < 16; mask <<= 1) {
                mx = fmaxf(mx, __shfl_xor(mx, mask));
                mn = fminf(mn, __shfl_xor(mn, mask));
            }
            if (m16 == 0) {
                pmax[(size_t)jblk * NROWS + row] = mx;
                pmin[(size_t)jblk * NROWS + row] = mn;
            }
        }
}

// ---------------------------------------------------------------------------
// Kernel 3: combine chunk partials, per-row loss, sum -> d_out[0]
// ---------------------------------------------------------------------------
__global__ __launch_bounds__(256) void finalize(const float* __restrict__ sqp,
                                                const float* __restrict__ pmax,
                                                const float* __restrict__ pmin,
                                                float* __restrict__ out) {
    __shared__ float wsum[4];
    const int i = blockIdx.x * 256 + threadIdx.x;
    float mp = -INFINITY, mn = INFINITY;
#pragma unroll
    for (int c = 0; c < NJB; ++c) {
        mp = fmaxf(mp, pmax[c * NROWS + i]);
        mn = fminf(mn, pmin[c * NROWS + i]);
    }
    const float si = sqp[i] + sqp[NROWS + i] + sqp[2 * NROWS + i] + sqp[3 * NROWS + i];
    const float hp = sqrtf(fmaxf(si + mp, 0.0f));
    const float hn = sqrtf(fmaxf(si + mn, 0.0f));
    const float d  = hp - hn;
    float li = fmaxf(d, 0.0f) + log1pf(expf(-fabsf(d)));  // stable log1p(exp(d))
#pragma unroll
    for (int off = 32; off; off >>= 1) li += __shfl_down(li, off);
    const int lane = threadIdx.x & 63, wv = threadIdx.x >> 6;
    if (lane == 0) wsum[wv] = li;
    __syncthreads();
    if (threadIdx.x == 0)
        atomicAdd(out, wsum[0] + wsum[1] + wsum[2] + wsum[3]);
}

// ---------------------------------------------------------------------------
extern "C" void kernel_launch(void* const* d_in, const int* in_sizes, int n_in,
                              void* d_out, int out_size, void* d_ws, size_t ws_size,
                              hipStream_t stream) {
    const float* x       = (const float*)d_in[0];
    const float* W       = (const float*)d_in[1];
    const float* b       = (const float*)d_in[2];
    const int*   targets = (const int*)d_in[3];
    float* out = (float*)d_out;

    unsigned short* WbT  = (unsigned short*)d_ws;               // 256*1024 bf16
    unsigned short* hs   = WbT + DOUT * DIN;                    // 4096*256 bf16 (fragment order)
    float*          sqp  = (float*)(hs + NROWS * DOUT);         // [4][4096]
    float*          pmax = sqp + NSQP * NROWS;                  // [64][4096]
    float*          pmin = pmax + NJB * NROWS;                  // [64][4096]

    hipMemsetAsync(d_out, 0, sizeof(float), stream);

    wconv<<<dim3(DOUT / 32, DIN / 32), 256, 0, stream>>>(W, WbT);
    gemm1_mfma<<<dim3(NSQP, NROWS / 16), 256, 0, stream>>>(x, WbT, b, hs, sqp);
    hardest_reg<<<dim3(NROWS / 128, NROWS / 128), 256, 0, stream>>>(hs, sqp, targets, pmax, pmin);
    finalize<<<NROWS / 256, 256, 0, stream>>>(sqp, pmax, pmin, out);
}

// Round 7
// 130.629 us; speedup vs baseline: 1.9676x; 1.0941x over previous
//
#include <hip/hip_runtime.h>
#include <math.h>

#define NROWS 4096
#define DIN   1024
#define DOUT  256
#define NJB   64         // 64-col j-chunks for pmax/pmin partials

using bfrag = __attribute__((ext_vector_type(8))) short;  // 8 bf16 (4 VGPRs)
using ffrag = __attribute__((ext_vector_type(4))) float;  // 4 fp32 acc

// Fragment-order layouts (mfma_f32_16x16x32_bf16; A and B share the per-lane
// map: elem[lane l][j] = M[tile*16 + (l&15)][ks*32 + (l>>4)*8 + j]):
//   xs: frag f = (t*32 + ks)*64 + l      t<256 (x row-tiles), ks<32 (K=1024)
//   Ws: frag f = (nt*32 + ks)*64 + l     nt<16 (W col-tiles), ks<32
//   hs: frag f = (t*8  + ks)*64 + l      t<256 (h row-tiles), ks<8  (K=256)

static __device__ __forceinline__ unsigned short f2bf(float f) {
    unsigned int u = __float_as_uint(f);
    u = (u + 0x7fffu + ((u >> 16) & 1u)) >> 16;
    return (unsigned short)u;
}
static __device__ __forceinline__ unsigned int pack2(float lo, float hi) {
    return (unsigned int)f2bf(lo) | ((unsigned int)f2bf(hi) << 16);
}

// ---------------------------------------------------------------------------
// Kernel A: xs = bf16(x) in A-fragment order. One 16B frag per thread.
// Reads 2 float4 per thread (32B contiguous); writes uint4 coalesced.
// ---------------------------------------------------------------------------
__global__ __launch_bounds__(256) void xconv(const float* __restrict__ x,
                                             unsigned short* __restrict__ xs) {
    const int f  = blockIdx.x * 256 + threadIdx.x;   // 524288 frags
    const int l  = f & 63;
    const int ks = (f >> 6) & 31;
    const int t  = f >> 11;
    const int row = t * 16 + (l & 15);
    const int k0  = ks * 32 + (l >> 4) * 8;
    const float4 p0 = *(const float4*)&x[(size_t)row * DIN + k0];
    const float4 p1 = *(const float4*)&x[(size_t)row * DIN + k0 + 4];
    uint4 v;
    v.x = pack2(p0.x, p0.y);
    v.y = pack2(p0.z, p0.w);
    v.z = pack2(p1.x, p1.y);
    v.w = pack2(p1.z, p1.w);
    *(uint4*)&xs[(size_t)f * 8] = v;
}

// ---------------------------------------------------------------------------
// Kernel B: Ws = bf16(W) in B-fragment order (gather; W is 1MB, L2-resident).
// ---------------------------------------------------------------------------
__global__ __launch_bounds__(256) void wconv(const float* __restrict__ W,
                                             unsigned short* __restrict__ Ws) {
    const int f  = blockIdx.x * 256 + threadIdx.x;   // 32768 frags
    const int l  = f & 63;
    const int ks = (f >> 6) & 31;
    const int nt = f >> 11;
    const int col = nt * 16 + (l & 15);
    const int k0  = ks * 32 + (l >> 4) * 8;
    uint4 v;
    float a[8];
#pragma unroll
    for (int j = 0; j < 8; ++j) a[j] = W[(size_t)(k0 + j) * DOUT + col];
    v.x = pack2(a[0], a[1]);
    v.y = pack2(a[2], a[3]);
    v.z = pack2(a[4], a[5]);
    v.w = pack2(a[6], a[7]);
    *(uint4*)&Ws[(size_t)f * 8] = v;
}

// ---------------------------------------------------------------------------
// Kernel 1: h = x@W + b, register-direct MFMA, NO barriers in the K-loop.
// One 16x16 output tile per wave: t = gw>>4, nt = gw&15; 32 ks iterations of
// (2 coalesced frag loads + 1 MFMA). Epilogue: per-wave LDS transpose -> hs
// fragment-order store; row-sq partial -> atomicAdd into sq (pre-zeroed).
// ---------------------------------------------------------------------------
__global__ __launch_bounds__(256) void gemm1_reg(
    const unsigned short* __restrict__ xs, const unsigned short* __restrict__ Ws,
    const float* __restrict__ b,
    unsigned short* __restrict__ hs, float* __restrict__ sq) {
    __shared__ __align__(16) short T[4][16][24];     // per-wave 16x16 tile (+pad)

    const int tid = threadIdx.x;
    const int w   = tid >> 6;
    const int l   = tid & 63;
    const int m16 = l & 15;
    const int q   = l >> 4;
    const int gw  = blockIdx.x * 4 + w;
    const int t   = gw >> 4;     // x row-tile (0..255)
    const int nt  = gw & 15;     // feature tile (0..15)

    const bfrag* A = (const bfrag*)xs + ((size_t)t * 32) * 64 + l;
    const bfrag* B = (const bfrag*)Ws + ((size_t)nt * 32) * 64 + l;

    ffrag acc = {};
#pragma unroll
    for (int ks = 0; ks < 32; ++ks)
        acc = __builtin_amdgcn_mfma_f32_16x16x32_bf16(A[ks * 64], B[ks * 64], acc, 0, 0, 0);

    // bias
    const float bc = b[nt * 16 + m16];
    float hv[4];
#pragma unroll
    for (int reg = 0; reg < 4; ++reg) hv[reg] = acc[reg] + bc;

    // row-sq partial: row = t*16 + q*4 + reg; sum over this wave's 16 features
#pragma unroll
    for (int reg = 0; reg < 4; ++reg) {
        float p = hv[reg] * hv[reg];
#pragma unroll
        for (int mask = 1; mask < 16; mask <<= 1) p += __shfl_xor(p, mask);
        if (m16 == 0) atomicAdd(&sq[t * 16 + q * 4 + reg], p);
    }

    // transpose C-tile (row=q*4+reg, col=m16) to h-row-major via LDS
#pragma unroll
    for (int reg = 0; reg < 4; ++reg)
        T[w][q * 4 + reg][m16] = f2bf(hv[reg]);
    // same-wave LDS RAW: compiler inserts lgkmcnt wait; no __syncthreads needed

    const int ksH  = nt >> 1;         // hs k-slice (32 features)
    const int half = nt & 1;
    const int qp   = q - 2 * half;    // 0..1 for this wave's half of the frag
    if (qp >= 0 && qp < 2) {
        bfrag v = *(const bfrag*)&T[w][m16][qp * 8];
        ((bfrag*)hs)[((size_t)t * 8 + ksH) * 64 + l] = v;   // half-wave 512B store
    }
}

// ---------------------------------------------------------------------------
// Kernel 2: register-direct Gram from fragment-order hs. No LDS, no barriers.
// Block = 128i x 128j; 4 waves in 2x2, each wave a 64x64 tile.
// Fused masked max/min on (sq_j - 2g); partials [NJB=64][4096].
// ---------------------------------------------------------------------------
__global__ __launch_bounds__(256) void hardest_reg(
    const unsigned short* __restrict__ hs, const float* __restrict__ sq,
    const int* __restrict__ targets,
    float* __restrict__ pmax, float* __restrict__ pmin) {
    const int tid = threadIdx.x;
    const int w   = tid >> 6;
    const int wi  = w & 1, wj = w >> 1;
    const int l   = tid & 63;
    const int m16 = l & 15;
    const int q   = l >> 4;
    const int i0  = blockIdx.y * 128;
    const int j0  = blockIdx.x * 128;
    const int iw  = i0 + wi * 64;
    const int jw  = j0 + wj * 64;
    const int tA  = iw >> 4;
    const int tB  = jw >> 4;

    ffrag acc[4][4] = {};                        // [mi][nj]

#pragma unroll
    for (int ks = 0; ks < 8; ++ks) {
        bfrag a[4], bb[4];
#pragma unroll
        for (int mi = 0; mi < 4; ++mi)
            a[mi] = *(const bfrag*)&hs[(((size_t)(tA + mi) * 8 + ks) * 64 + l) * 8];
#pragma unroll
        for (int nj = 0; nj < 4; ++nj)
            bb[nj] = *(const bfrag*)&hs[(((size_t)(tB + nj) * 8 + ks) * 64 + l) * 8];
#pragma unroll
        for (int mi = 0; mi < 4; ++mi)
#pragma unroll
            for (int nj = 0; nj < 4; ++nj)
                acc[mi][nj] = __builtin_amdgcn_mfma_f32_16x16x32_bf16(
                    a[mi], bb[nj], acc[mi][nj], 0, 0, 0);
    }

    // ---- fused epilogue: masked running max/min on (sq_j - 2*g) ----
    int   tj[4];
    float sv[4];
#pragma unroll
    for (int nj = 0; nj < 4; ++nj) {
        const int col = jw + nj * 16 + m16;
        tj[nj] = targets[col];
        sv[nj] = sq[col];
    }

    const int jblk = blockIdx.x * 2 + wj;        // 64-col chunk index (0..63)
#pragma unroll
    for (int mi = 0; mi < 4; ++mi)
#pragma unroll
        for (int reg = 0; reg < 4; ++reg) {
            const int row = iw + mi * 16 + q * 4 + reg;
            const int ti  = targets[row];
            float mx = -INFINITY, mn = INFINITY;
#pragma unroll
            for (int nj = 0; nj < 4; ++nj) {
                const float v = fmaf(-2.0f, acc[mi][nj][reg], sv[nj]);
                if (tj[nj] == ti) mx = fmaxf(mx, v);
                else              mn = fminf(mn, v);
            }
#pragma unroll
            for (int mask = 1; mask < 16; mask <<= 1) {
                mx = fmaxf(mx, __shfl_xor(mx, mask));
                mn = fminf(mn, __shfl_xor(mn, mask));
            }
            if (m16 == 0) {
                pmax[(size_t)jblk * NROWS + row] = mx;
                pmin[(size_t)jblk * NROWS + row] = mn;
            }
        }
}

// ---------------------------------------------------------------------------
// Kernel 3: combine chunk partials, per-row loss, sum -> d_out[0]
// ---------------------------------------------------------------------------
__global__ __launch_bounds__(256) void finalize(const float* __restrict__ sq,
                                                const float* __restrict__ pmax,
                                                const float* __restrict__ pmin,
                                                float* __restrict__ out) {
    __shared__ float wsum[4];
    const int i = blockIdx.x * 256 + threadIdx.x;
    float mp = -INFINITY, mn = INFINITY;
#pragma unroll
    for (int c = 0; c < NJB; ++c) {
        mp = fmaxf(mp, pmax[c * NROWS + i]);
        mn = fminf(mn, pmin[c * NROWS + i]);
    }
    const float si = sq[i];
    const float hp = sqrtf(fmaxf(si + mp, 0.0f));
    const float hn = sqrtf(fmaxf(si + mn, 0.0f));
    const float d  = hp - hn;
    float li = fmaxf(d, 0.0f) + log1pf(expf(-fabsf(d)));  // stable log1p(exp(d))
#pragma unroll
    for (int off = 32; off; off >>= 1) li += __shfl_down(li, off);
    const int lane = threadIdx.x & 63, wv = threadIdx.x >> 6;
    if (lane == 0) wsum[wv] = li;
    __syncthreads();
    if (threadIdx.x == 0)
        atomicAdd(out, wsum[0] + wsum[1] + wsum[2] + wsum[3]);
}

// ---------------------------------------------------------------------------
extern "C" void kernel_launch(void* const* d_in, const int* in_sizes, int n_in,
                              void* d_out, int out_size, void* d_ws, size_t ws_size,
                              hipStream_t stream) {
    const float* x       = (const float*)d_in[0];
    const float* W       = (const float*)d_in[1];
    const float* b       = (const float*)d_in[2];
    const int*   targets = (const int*)d_in[3];
    float* out = (float*)d_out;

    unsigned short* Ws   = (unsigned short*)d_ws;               // 256*1024 bf16 (frag order)
    unsigned short* xs   = Ws + DOUT * DIN;                     // 4096*1024 bf16 (frag order)
    unsigned short* hs   = xs + (size_t)NROWS * DIN;            // 4096*256 bf16 (frag order)
    float*          sq   = (float*)(hs + NROWS * DOUT);         // 4096
    float*          pmax = sq + NROWS;                          // [64][4096]
    float*          pmin = pmax + NJB * NROWS;                  // [64][4096]

    hipMemsetAsync(d_out, 0, sizeof(float), stream);
    hipMemsetAsync(sq, 0, NROWS * sizeof(float), stream);

    xconv<<<(NROWS / 16) * 32 * 64 / 256, 256, 0, stream>>>(x, xs);
    wconv<<<16 * 32 * 64 / 256, 256, 0, stream>>>(W, Ws);
    gemm1_reg<<<NROWS / 16 * 16 / 4, 256, 0, stream>>>(xs, Ws, b, hs, sq);
    hardest_reg<<<dim3(NROWS / 128, NROWS / 128), 256, 0, stream>>>(hs, sq, targets, pmax, pmin);
    finalize<<<NROWS / 256, 256, 0, stream>>>(sq, pmax, pmin, out);
}

// Round 9
// 126.980 us; speedup vs baseline: 2.0242x; 1.0287x over previous
//
#include <hip/hip_runtime.h>
#include <math.h>

#define NROWS 4096
#define DIN   1024
#define DOUT  256
#define NJB   64         // 64-col j-chunks for pmax/pmin partials

using bfrag = __attribute__((ext_vector_type(8))) short;  // 8 bf16 (4 VGPRs)
using ffrag = __attribute__((ext_vector_type(4))) float;  // 4 fp32 acc

// Fragment-order layouts (mfma_f32_16x16x32_bf16; A and B share the per-lane
// map: elem[lane l][j] = M[tile*16 + (l&15)][ks*32 + (l>>4)*8 + j]):
//   xs: frag f = (t*32 + ks)*64 + l      t<256 (x row-tiles), ks<32 (K=1024)
//   Ws: frag f = (nt*32 + ks)*64 + l     nt<16 (W col-tiles), ks<32
//   hs: frag f = (t*8  + ks)*64 + l      t<256 (h row-tiles), ks<8  (K=256)

static __device__ __forceinline__ unsigned short f2bf(float f) {
    unsigned int u = __float_as_uint(f);
    u = (u + 0x7fffu + ((u >> 16) & 1u)) >> 16;
    return (unsigned short)u;
}
static __device__ __forceinline__ unsigned int pack2(float lo, float hi) {
    return (unsigned int)f2bf(lo) | ((unsigned int)f2bf(hi) << 16);
}

// ---------------------------------------------------------------------------
// Kernel 0 (setup): xs & Ws fragment conversion + sq/out zeroing, one dispatch.
// Grid 2048 x 256: thread f converts one xs frag; f<32768 also one Ws frag;
// f<4096 zeroes sq[f]; f==0 zeroes *out. Consumers are later dispatches on
// the same stream (kernel-boundary ordering gives visibility).
// ---------------------------------------------------------------------------
__global__ __launch_bounds__(256) void setup(const float* __restrict__ x,
                                             const float* __restrict__ W,
                                             unsigned short* __restrict__ xs,
                                             unsigned short* __restrict__ Ws,
                                             float* __restrict__ sq,
                                             float* __restrict__ out) {
    const int f  = blockIdx.x * 256 + threadIdx.x;   // 524288 xs frags
    {
        const int l  = f & 63;
        const int ks = (f >> 6) & 31;
        const int t  = f >> 11;
        const int row = t * 16 + (l & 15);
        const int k0  = ks * 32 + (l >> 4) * 8;
        const float4 p0 = *(const float4*)&x[(size_t)row * DIN + k0];
        const float4 p1 = *(const float4*)&x[(size_t)row * DIN + k0 + 4];
        uint4 v;
        v.x = pack2(p0.x, p0.y);
        v.y = pack2(p0.z, p0.w);
        v.z = pack2(p1.x, p1.y);
        v.w = pack2(p1.z, p1.w);
        *(uint4*)&xs[(size_t)f * 8] = v;
    }
    if (f < 32768) {                                 // Ws frags
        const int l  = f & 63;
        const int ks = (f >> 6) & 31;
        const int nt = f >> 11;
        const int col = nt * 16 + (l & 15);
        const int k0  = ks * 32 + (l >> 4) * 8;
        float a[8];
#pragma unroll
        for (int j = 0; j < 8; ++j) a[j] = W[(size_t)(k0 + j) * DOUT + col];
        uint4 v;
        v.x = pack2(a[0], a[1]);
        v.y = pack2(a[2], a[3]);
        v.z = pack2(a[4], a[5]);
        v.w = pack2(a[6], a[7]);
        *(uint4*)&Ws[(size_t)f * 8] = v;
    }
    if (f < NROWS) sq[f] = 0.0f;
    if (f == 0) *out = 0.0f;
}

// ---------------------------------------------------------------------------
// Kernel 1: h = x@W + b, register-direct MFMA, NO barriers in the K-loop.
// One 16x16 output tile per wave: 32 ks of (2 coalesced frag loads + 1 MFMA).
// Epilogue: per-wave LDS transpose -> hs fragment-order store; row-sq partial
// -> atomicAdd into sq (zeroed by setup).
// ---------------------------------------------------------------------------
__global__ __launch_bounds__(256) void gemm1_reg(
    const unsigned short* __restrict__ xs, const unsigned short* __restrict__ Ws,
    const float* __restrict__ b,
    unsigned short* __restrict__ hs, float* __restrict__ sq) {
    __shared__ __align__(16) short T[4][16][24];     // per-wave 16x16 tile (+pad)

    const int tid = threadIdx.x;
    const int w   = tid >> 6;
    const int l   = tid & 63;
    const int m16 = l & 15;
    const int q   = l >> 4;
    const int gw  = blockIdx.x * 4 + w;
    const int t   = gw >> 4;     // x row-tile (0..255)
    const int nt  = gw & 15;     // feature tile (0..15)

    const bfrag* A = (const bfrag*)xs + ((size_t)t * 32) * 64 + l;
    const bfrag* B = (const bfrag*)Ws + ((size_t)nt * 32) * 64 + l;

    ffrag acc = {};
#pragma unroll
    for (int ks = 0; ks < 32; ++ks)
        acc = __builtin_amdgcn_mfma_f32_16x16x32_bf16(A[ks * 64], B[ks * 64], acc, 0, 0, 0);

    const float bc = b[nt * 16 + m16];
    float hv[4];
#pragma unroll
    for (int reg = 0; reg < 4; ++reg) hv[reg] = acc[reg] + bc;

    // row-sq partial: row = t*16 + q*4 + reg; sum over this wave's 16 features
#pragma unroll
    for (int reg = 0; reg < 4; ++reg) {
        float p = hv[reg] * hv[reg];
#pragma unroll
        for (int mask = 1; mask < 16; mask <<= 1) p += __shfl_xor(p, mask);
        if (m16 == 0) atomicAdd(&sq[t * 16 + q * 4 + reg], p);
    }

    // transpose C-tile (row=q*4+reg, col=m16) to h-row-major via LDS
#pragma unroll
    for (int reg = 0; reg < 4; ++reg)
        T[w][q * 4 + reg][m16] = f2bf(hv[reg]);
    // same-wave LDS RAW: compiler inserts lgkmcnt wait; no __syncthreads needed

    const int ksH  = nt >> 1;         // hs k-slice (32 features)
    const int half = nt & 1;
    const int qp   = q - 2 * half;    // 0..1 for this wave's half of the frag
    if (qp >= 0 && qp < 2) {
        bfrag v = *(const bfrag*)&T[w][m16][qp * 8];
        ((bfrag*)hs)[((size_t)t * 8 + ksH) * 64 + l] = v;   // half-wave 512B store
    }
}

// ---------------------------------------------------------------------------
// Kernel 2: register-direct Gram from fragment-order hs. No LDS, no barriers.
// Block = 128i x 128j; 4 waves in 2x2, each wave a 64x64 tile.
// Fused masked max/min on (sq_j - 2g); partials [NJB=64][4096].
// ---------------------------------------------------------------------------
__global__ __launch_bounds__(256) void hardest_reg(
    const unsigned short* __restrict__ hs, const float* __restrict__ sq,
    const int* __restrict__ targets,
    float* __restrict__ pmax, float* __restrict__ pmin) {
    const int tid = threadIdx.x;
    const int w   = tid >> 6;
    const int wi  = w & 1, wj = w >> 1;
    const int l   = tid & 63;
    const int m16 = l & 15;
    const int q   = l >> 4;
    const int i0  = blockIdx.y * 128;
    const int j0  = blockIdx.x * 128;
    const int iw  = i0 + wi * 64;
    const int jw  = j0 + wj * 64;
    const int tA  = iw >> 4;
    const int tB  = jw >> 4;

    ffrag acc[4][4] = {};                        // [mi][nj]

#pragma unroll
    for (int ks = 0; ks < 8; ++ks) {
        bfrag a[4], bb[4];
#pragma unroll
        for (int mi = 0; mi < 4; ++mi)
            a[mi] = *(const bfrag*)&hs[(((size_t)(tA + mi) * 8 + ks) * 64 + l) * 8];
#pragma unroll
        for (int nj = 0; nj < 4; ++nj)
            bb[nj] = *(const bfrag*)&hs[(((size_t)(tB + nj) * 8 + ks) * 64 + l) * 8];
#pragma unroll
        for (int mi = 0; mi < 4; ++mi)
#pragma unroll
            for (int nj = 0; nj < 4; ++nj)
                acc[mi][nj] = __builtin_amdgcn_mfma_f32_16x16x32_bf16(
                    a[mi], bb[nj], acc[mi][nj], 0, 0, 0);
    }

    // ---- fused epilogue: masked running max/min on (sq_j - 2*g) ----
    int   tj[4];
    float sv[4];
#pragma unroll
    for (int nj = 0; nj < 4; ++nj) {
        const int col = jw + nj * 16 + m16;
        tj[nj] = targets[col];
        sv[nj] = sq[col];
    }

    const int jblk = blockIdx.x * 2 + wj;        // 64-col chunk index (0..63)
#pragma unroll
    for (int mi = 0; mi < 4; ++mi)
#pragma unroll
        for (int reg = 0; reg < 4; ++reg) {
            const int row = iw + mi * 16 + q * 4 + reg;
            const int ti  = targets[row];
            float mx = -INFINITY, mn = INFINITY;
#pragma unroll
            for (int nj = 0; nj < 4; ++nj) {
                const float v = fmaf(-2.0f, acc[mi][nj][reg], sv[nj]);
                if (tj[nj] == ti) mx = fmaxf(mx, v);
                else              mn = fminf(mn, v);
            }
#pragma unroll
            for (int mask = 1; mask < 16; mask <<= 1) {
                mx = fmaxf(mx, __shfl_xor(mx, mask));
                mn = fminf(mn, __shfl_xor(mn, mask));
            }
            if (m16 == 0) {
                pmax[(size_t)jblk * NROWS + row] = mx;
                pmin[(size_t)jblk * NROWS + row] = mn;
            }
        }
}

// ---------------------------------------------------------------------------
// Kernel 3: combine chunk partials, per-row loss, sum -> out[0]
// ---------------------------------------------------------------------------
__global__ __launch_bounds__(256) void finalize(const float* __restrict__ sq,
                                                const float* __restrict__ pmax,
                                                const float* __restrict__ pmin,
                                                float* __restrict__ out) {
    __shared__ float wsum[4];
    const int i = blockIdx.x * 256 + threadIdx.x;
    float mp = -INFINITY, mn = INFINITY;
#pragma unroll
    for (int c = 0; c < NJB; ++c) {
        mp = fmaxf(mp, pmax[c * NROWS + i]);
        mn = fminf(mn, pmin[c * NROWS + i]);
    }
    const float si = sq[i];
    const float hp = sqrtf(fmaxf(si + mp, 0.0f));
    const float hn = sqrtf(fmaxf(si + mn, 0.0f));
    const float d  = hp - hn;
    float li = fmaxf(d, 0.0f) + log1pf(expf(-fabsf(d)));  // stable log1p(exp(d))
#pragma unroll
    for (int off = 32; off; off >>= 1) li += __shfl_down(li, off);
    const int lane = threadIdx.x & 63, wv = threadIdx.x >> 6;
    if (lane == 0) wsum[wv] = li;
    __syncthreads();
    if (threadIdx.x == 0)
        atomicAdd(out, wsum[0] + wsum[1] + wsum[2] + wsum[3]);
}

// ---------------------------------------------------------------------------
extern "C" void kernel_launch(void* const* d_in, const int* in_sizes, int n_in,
                              void* d_out, int out_size, void* d_ws, size_t ws_size,
                              hipStream_t stream) {
    const float* x       = (const float*)d_in[0];
    const float* W       = (const float*)d_in[1];
    const float* b       = (const float*)d_in[2];
    const int*   targets = (const int*)d_in[3];
    float* out = (float*)d_out;

    unsigned short* Ws   = (unsigned short*)d_ws;               // 256*1024 bf16 (frag order)
    unsigned short* xs   = Ws + DOUT * DIN;                     // 4096*1024 bf16 (frag order)
    unsigned short* hs   = xs + (size_t)NROWS * DIN;            // 4096*256 bf16 (frag order)
    float*          sq   = (float*)(hs + NROWS * DOUT);         // 4096
    float*          pmax = sq + NROWS;                          // [64][4096]
    float*          pmin = pmax + NJB * NROWS;                  // [64][4096]

    setup<<<(NROWS / 16) * 32 * 64 / 256, 256, 0, stream>>>(x, W, xs, Ws, sq, out);
    gemm1_reg<<<NROWS / 16 * 16 / 4, 256, 0, stream>>>(xs, Ws, b, hs, sq);
    hardest_reg<<<dim3(NROWS / 128, NROWS / 128), 256, 0, stream>>>(hs, sq, targets, pmax, pmin);
    finalize<<<NROWS / 256, 256, 0, stream>>>(sq, pmax, pmin, out);
}

// Round 10
// 121.567 us; speedup vs baseline: 2.1143x; 1.0445x over previous
//
#include <hip/hip_runtime.h>
#include <math.h>

#define NROWS 4096
#define DIN   1024
#define DOUT  256
#define NJB   64         // 64-col j-chunks for pmax/pmin partials
#define NPAIR 528        // 32*33/2 triangular 128x128 block pairs

using bfrag = __attribute__((ext_vector_type(8))) short;  // 8 bf16 (4 VGPRs)
using ffrag = __attribute__((ext_vector_type(4))) float;  // 4 fp32 acc

// Fragment-order layouts (mfma_f32_16x16x32_bf16; A and B share the per-lane
// map: elem[lane l][j] = M[tile*16 + (l&15)][ks*32 + (l>>4)*8 + j]):
//   xs: frag f = (t*32 + ks)*64 + l      t<256 (x row-tiles), ks<32 (K=1024)
//   Ws: frag f = (nt*32 + ks)*64 + l     nt<16 (W col-tiles), ks<32
//   hs: frag f = (t*8  + ks)*64 + l      t<256 (h row-tiles), ks<8  (K=256)

static __device__ __forceinline__ unsigned short f2bf(float f) {
    unsigned int u = __float_as_uint(f);
    u = (u + 0x7fffu + ((u >> 16) & 1u)) >> 16;
    return (unsigned short)u;
}
static __device__ __forceinline__ unsigned int pack2(float lo, float hi) {
    return (unsigned int)f2bf(lo) | ((unsigned int)f2bf(hi) << 16);
}

// ---------------------------------------------------------------------------
// Kernel 0 (setup): xs & Ws fragment conversion + sq/out zeroing, one dispatch.
// ---------------------------------------------------------------------------
__global__ __launch_bounds__(256) void setup(const float* __restrict__ x,
                                             const float* __restrict__ W,
                                             unsigned short* __restrict__ xs,
                                             unsigned short* __restrict__ Ws,
                                             float* __restrict__ sq,
                                             float* __restrict__ out) {
    const int f  = blockIdx.x * 256 + threadIdx.x;   // 524288 xs frags
    {
        const int l  = f & 63;
        const int ks = (f >> 6) & 31;
        const int t  = f >> 11;
        const int row = t * 16 + (l & 15);
        const int k0  = ks * 32 + (l >> 4) * 8;
        const float4 p0 = *(const float4*)&x[(size_t)row * DIN + k0];
        const float4 p1 = *(const float4*)&x[(size_t)row * DIN + k0 + 4];
        uint4 v;
        v.x = pack2(p0.x, p0.y);
        v.y = pack2(p0.z, p0.w);
        v.z = pack2(p1.x, p1.y);
        v.w = pack2(p1.z, p1.w);
        *(uint4*)&xs[(size_t)f * 8] = v;
    }
    if (f < 32768) {                                 // Ws frags
        const int l  = f & 63;
        const int ks = (f >> 6) & 31;
        const int nt = f >> 11;
        const int col = nt * 16 + (l & 15);
        const int k0  = ks * 32 + (l >> 4) * 8;
        float a[8];
#pragma unroll
        for (int j = 0; j < 8; ++j) a[j] = W[(size_t)(k0 + j) * DOUT + col];
        uint4 v;
        v.x = pack2(a[0], a[1]);
        v.y = pack2(a[2], a[3]);
        v.z = pack2(a[4], a[5]);
        v.w = pack2(a[6], a[7]);
        *(uint4*)&Ws[(size_t)f * 8] = v;
    }
    if (f < NROWS) sq[f] = 0.0f;
    if (f == 0) *out = 0.0f;
}

// ---------------------------------------------------------------------------
// Kernel 1: h = x@W + b, register-direct MFMA, NO barriers in the K-loop.
// ---------------------------------------------------------------------------
__global__ __launch_bounds__(256) void gemm1_reg(
    const unsigned short* __restrict__ xs, const unsigned short* __restrict__ Ws,
    const float* __restrict__ b,
    unsigned short* __restrict__ hs, float* __restrict__ sq) {
    __shared__ __align__(16) short T[4][16][24];     // per-wave 16x16 tile (+pad)

    const int tid = threadIdx.x;
    const int w   = tid >> 6;
    const int l   = tid & 63;
    const int m16 = l & 15;
    const int q   = l >> 4;
    const int gw  = blockIdx.x * 4 + w;
    const int t   = gw >> 4;     // x row-tile (0..255)
    const int nt  = gw & 15;     // feature tile (0..15)

    const bfrag* A = (const bfrag*)xs + ((size_t)t * 32) * 64 + l;
    const bfrag* B = (const bfrag*)Ws + ((size_t)nt * 32) * 64 + l;

    ffrag acc = {};
#pragma unroll
    for (int ks = 0; ks < 32; ++ks)
        acc = __builtin_amdgcn_mfma_f32_16x16x32_bf16(A[ks * 64], B[ks * 64], acc, 0, 0, 0);

    const float bc = b[nt * 16 + m16];
    float hv[4];
#pragma unroll
    for (int reg = 0; reg < 4; ++reg) hv[reg] = acc[reg] + bc;

    // row-sq partial: row = t*16 + q*4 + reg; sum over this wave's 16 features
#pragma unroll
    for (int reg = 0; reg < 4; ++reg) {
        float p = hv[reg] * hv[reg];
#pragma unroll
        for (int mask = 1; mask < 16; mask <<= 1) p += __shfl_xor(p, mask);
        if (m16 == 0) atomicAdd(&sq[t * 16 + q * 4 + reg], p);
    }

    // transpose C-tile (row=q*4+reg, col=m16) to h-row-major via LDS
#pragma unroll
    for (int reg = 0; reg < 4; ++reg)
        T[w][q * 4 + reg][m16] = f2bf(hv[reg]);
    // same-wave LDS RAW: compiler inserts lgkmcnt wait; no __syncthreads needed

    const int ksH  = nt >> 1;         // hs k-slice (32 features)
    const int half = nt & 1;
    const int qp   = q - 2 * half;    // 0..1 for this wave's half of the frag
    if (qp >= 0 && qp < 2) {
        bfrag v = *(const bfrag*)&T[w][m16][qp * 8];
        ((bfrag*)hs)[((size_t)t * 8 + ksH) * 64 + l] = v;   // half-wave 512B store
    }
}

// ---------------------------------------------------------------------------
// Kernel 2: triangular register-direct Gram (g = g^T computed once per pair).
// Grid = 528 pairs (bi<=bj) of 128x128 tiles; 4 waves in 2x2, 64x64 each.
// Row-anchors: max/min of (sq_j - 2g) reduced over m16 lanes -> [bj-chunk][row].
// Col-anchors: max/min of (sq_i - 2g) reduced over reg+q    -> [bi-chunk][col].
// Diagonal pairs emit row-side only (col-side would duplicate cells).
// Every [chunk][anchor] cell written exactly once; no atomics.
// ---------------------------------------------------------------------------
__global__ __launch_bounds__(256) void hardest_tri(
    const unsigned short* __restrict__ hs, const float* __restrict__ sq,
    const int* __restrict__ targets,
    float* __restrict__ pmax, float* __restrict__ pmin) {
    const int tid = threadIdx.x;
    const int w   = tid >> 6;
    const int wi  = w & 1, wj = w >> 1;
    const int l   = tid & 63;
    const int m16 = l & 15;
    const int q   = l >> 4;

    // decode triangular pair index k -> (bi <= bj)
    const int k = blockIdx.x;
    int bj = (int)((sqrtf(8.0f * (float)k + 1.0f) - 1.0f) * 0.5f);
    while ((bj + 1) * (bj + 2) / 2 <= k) ++bj;
    while (bj * (bj + 1) / 2 > k) --bj;
    const int bi = k - bj * (bj + 1) / 2;
    const bool diag = (bi == bj);

    const int iw = bi * 128 + wi * 64;
    const int jw = bj * 128 + wj * 64;
    const int tA = iw >> 4;
    const int tB = jw >> 4;

    ffrag acc[4][4] = {};                        // [mi][nj]

#pragma unroll
    for (int ks = 0; ks < 8; ++ks) {
        bfrag a[4], bb[4];
#pragma unroll
        for (int mi = 0; mi < 4; ++mi)
            a[mi] = *(const bfrag*)&hs[(((size_t)(tA + mi) * 8 + ks) * 64 + l) * 8];
#pragma unroll
        for (int nj = 0; nj < 4; ++nj)
            bb[nj] = *(const bfrag*)&hs[(((size_t)(tB + nj) * 8 + ks) * 64 + l) * 8];
#pragma unroll
        for (int mi = 0; mi < 4; ++mi)
#pragma unroll
            for (int nj = 0; nj < 4; ++nj)
                acc[mi][nj] = __builtin_amdgcn_mfma_f32_16x16x32_bf16(
                    a[mi], bb[nj], acc[mi][nj], 0, 0, 0);
    }

    // ---- fused epilogue, both directions ----
    int   tj[4];
    float svj[4];
#pragma unroll
    for (int nj = 0; nj < 4; ++nj) {
        const int col = jw + nj * 16 + m16;
        tj[nj]  = targets[col];
        svj[nj] = sq[col];
    }

    float cmx[4], cmn[4];
#pragma unroll
    for (int nj = 0; nj < 4; ++nj) { cmx[nj] = -INFINITY; cmn[nj] = INFINITY; }

    const int jblk = bj * 2 + wj;
#pragma unroll
    for (int mi = 0; mi < 4; ++mi)
#pragma unroll
        for (int reg = 0; reg < 4; ++reg) {
            const int row = iw + mi * 16 + q * 4 + reg;
            const int ti  = targets[row];
            const float si = sq[row];
            float mx = -INFINITY, mn = INFINITY;
#pragma unroll
            for (int nj = 0; nj < 4; ++nj) {
                const float g    = acc[mi][nj][reg];
                const float vrow = fmaf(-2.0f, g, svj[nj]);
                const float vcol = fmaf(-2.0f, g, si);
                if (tj[nj] == ti) {
                    mx = fmaxf(mx, vrow);
                    cmx[nj] = fmaxf(cmx[nj], vcol);
                } else {
                    mn = fminf(mn, vrow);
                    cmn[nj] = fminf(cmn[nj], vcol);
                }
            }
            // row-side: reduce over the 16 m16-lanes
#pragma unroll
            for (int mask = 1; mask < 16; mask <<= 1) {
                mx = fmaxf(mx, __shfl_xor(mx, mask));
                mn = fminf(mn, __shfl_xor(mn, mask));
            }
            if (m16 == 0) {
                pmax[(size_t)jblk * NROWS + row] = mx;
                pmin[(size_t)jblk * NROWS + row] = mn;
            }
        }

    // col-side: reduce over the q bits (lanes 16,32 apart), skip on diagonal
    if (!diag) {
        const int iblk = bi * 2 + wi;
#pragma unroll
        for (int nj = 0; nj < 4; ++nj) {
            float mx = cmx[nj], mn = cmn[nj];
            mx = fmaxf(mx, __shfl_xor(mx, 16));
            mn = fminf(mn, __shfl_xor(mn, 16));
            mx = fmaxf(mx, __shfl_xor(mx, 32));
            mn = fminf(mn, __shfl_xor(mn, 32));
            if (q == 0) {
                const int col = jw + nj * 16 + m16;
                pmax[(size_t)iblk * NROWS + col] = mx;
                pmin[(size_t)iblk * NROWS + col] = mn;
            }
        }
    }
}

// ---------------------------------------------------------------------------
// Kernel 3: combine chunk partials, per-row loss, sum -> out[0]
// ---------------------------------------------------------------------------
__global__ __launch_bounds__(256) void finalize(const float* __restrict__ sq,
                                                const float* __restrict__ pmax,
                                                const float* __restrict__ pmin,
                                                float* __restrict__ out) {
    __shared__ float wsum[4];
    const int i = blockIdx.x * 256 + threadIdx.x;
    float mp = -INFINITY, mn = INFINITY;
#pragma unroll
    for (int c = 0; c < NJB; ++c) {
        mp = fmaxf(mp, pmax[c * NROWS + i]);
        mn = fminf(mn, pmin[c * NROWS + i]);
    }
    const float si = sq[i];
    const float hp = sqrtf(fmaxf(si + mp, 0.0f));
    const float hn = sqrtf(fmaxf(si + mn, 0.0f));
    const float d  = hp - hn;
    float li = fmaxf(d, 0.0f) + log1pf(expf(-fabsf(d)));  // stable log1p(exp(d))
#pragma unroll
    for (int off = 32; off; off >>= 1) li += __shfl_down(li, off);
    const int lane = threadIdx.x & 63, wv = threadIdx.x >> 6;
    if (lane == 0) wsum[wv] = li;
    __syncthreads();
    if (threadIdx.x == 0)
        atomicAdd(out, wsum[0] + wsum[1] + wsum[2] + wsum[3]);
}

// ---------------------------------------------------------------------------
extern "C" void kernel_launch(void* const* d_in, const int* in_sizes, int n_in,
                              void* d_out, int out_size, void* d_ws, size_t ws_size,
                              hipStream_t stream) {
    const float* x       = (const float*)d_in[0];
    const float* W       = (const float*)d_in[1];
    const float* b       = (const float*)d_in[2];
    const int*   targets = (const int*)d_in[3];
    float* out = (float*)d_out;

    unsigned short* Ws   = (unsigned short*)d_ws;               // 256*1024 bf16 (frag order)
    unsigned short* xs   = Ws + DOUT * DIN;                     // 4096*1024 bf16 (frag order)
    unsigned short* hs   = xs + (size_t)NROWS * DIN;            // 4096*256 bf16 (frag order)
    float*          sq   = (float*)(hs + NROWS * DOUT);         // 4096
    float*          pmax = sq + NROWS;                          // [64][4096]
    float*          pmin = pmax + NJB * NROWS;                  // [64][4096]

    setup<<<(NROWS / 16) * 32 * 64 / 256, 256, 0, stream>>>(x, W, xs, Ws, sq, out);
    gemm1_reg<<<NROWS / 16 * 16 / 4, 256, 0, stream>>>(xs, Ws, b, hs, sq);
    hardest_tri<<<NPAIR, 256, 0, stream>>>(hs, sq, targets, pmax, pmin);
    finalize<<<NROWS / 256, 256, 0, stream>>>(sq, pmax, pmin, out);
}